// Round 3
// baseline (405.365 us; speedup 1.0000x reference)
//
#include <hip/hip_runtime.h>

#define IN_CH 16
#define HID 128
#define HEADS 4
#define NEG 0.2f
#define LN_EPS 1e-5f

typedef short bf16x8 __attribute__((ext_vector_type(8)));
typedef float f32x4 __attribute__((ext_vector_type(4)));

__device__ __forceinline__ float bf2f(unsigned short u) {
  return __uint_as_float(((unsigned)u) << 16);
}
__device__ __forceinline__ float bflo(unsigned u) {
  return __uint_as_float(u << 16);
}
__device__ __forceinline__ float bfhi(unsigned u) {
  return __uint_as_float(u & 0xffff0000u);
}
__device__ __forceinline__ unsigned short f2bf(float f) {
  unsigned u = __float_as_uint(f);
  unsigned r = (u + 0x7fffu + ((u >> 16) & 1u)) >> 16;  // RNE
  return (unsigned short)r;
}

// ---------------------------------------------------------------------------
// h1 = x @ W1 (N x 16 @ 16 x 128) -> bf16, fused per-head attention logits.
// (R1-verified)
// ---------------------------------------------------------------------------
__global__ __launch_bounds__(128) void k_gemm1(
    const float* __restrict__ x, const float* __restrict__ W1,
    const float* __restrict__ a_src, const float* __restrict__ a_dst,
    unsigned short* __restrict__ hb, float* __restrict__ asrc,
    float* __restrict__ adst, int N) {
  int n = blockIdx.x;
  int c = threadIdx.x;
  __shared__ float xs[IN_CH];
  if (c < IN_CH) xs[c] = x[n * IN_CH + c];
  __syncthreads();
  float acc = 0.f;
#pragma unroll
  for (int k = 0; k < IN_CH; ++k) acc += xs[k] * W1[k * HID + c];
  hb[(size_t)n * HID + c] = f2bf(acc);
  float av = acc * a_src[c];
  float dv = acc * a_dst[c];
#pragma unroll
  for (int o = 16; o > 0; o >>= 1) {
    av += __shfl_down(av, o, 32);
    dv += __shfl_down(dv, o, 32);
  }
  if ((c & 31) == 0) {
    asrc[n * HEADS + (c >> 5)] = av;
    adst[n * HEADS + (c >> 5)] = dv;
  }
}

// ---------------------------------------------------------------------------
// CSR build: degree count + per-edge rank. (R1-verified)
// ---------------------------------------------------------------------------
__global__ __launch_bounds__(256) void k_deg(
    const int* __restrict__ ei, int E, int Etot, int* __restrict__ deg,
    int* __restrict__ rank) {
  int e = blockIdx.x * 256 + threadIdx.x;
  if (e >= Etot) return;
  int d = (e < E) ? ei[E + e] : (e - E);
  rank[e] = atomicAdd(&deg[d], 1);
}

__global__ __launch_bounds__(256) void k_scan1(
    const int* __restrict__ deg, int* __restrict__ part, int* __restrict__ aux,
    int N) {
  int i = blockIdx.x * 256 + threadIdx.x;
  int v = (i < N) ? deg[i] : 0;
  int lane = threadIdx.x & 63, w = threadIdx.x >> 6;
  int inc = v;
#pragma unroll
  for (int o = 1; o < 64; o <<= 1) {
    int t = __shfl_up(inc, o, 64);
    if (lane >= o) inc += t;
  }
  __shared__ int wsum[4];
  if (lane == 63) wsum[w] = inc;
  __syncthreads();
  int woff = 0;
#pragma unroll
  for (int k = 0; k < 4; ++k)
    if (k < w) woff += wsum[k];
  if (i < N) part[i] = woff + inc - v;
  if (threadIdx.x == 255) aux[blockIdx.x] = woff + inc;
}

__global__ __launch_bounds__(512) void k_scan2(int* __restrict__ aux, int nb) {
  int i = threadIdx.x;
  int v = (i < nb) ? aux[i] : 0;
  int lane = i & 63, w = i >> 6;
  int inc = v;
#pragma unroll
  for (int o = 1; o < 64; o <<= 1) {
    int t = __shfl_up(inc, o, 64);
    if (lane >= o) inc += t;
  }
  __shared__ int wsum[8];
  if (lane == 63) wsum[w] = inc;
  __syncthreads();
  int woff = 0;
#pragma unroll
  for (int k = 0; k < 8; ++k)
    if (k < w) woff += wsum[k];
  if (i < nb) aux[i] = woff + inc - v;
}

__global__ __launch_bounds__(256) void k_scan3(
    const int* __restrict__ part, const int* __restrict__ aux,
    int* __restrict__ rowstart, int N, int Etot) {
  int i = blockIdx.x * 256 + threadIdx.x;
  if (i < N) rowstart[i] = part[i] + aux[blockIdx.x];
  if (i == 0) rowstart[N] = Etot;
}

// ---------------------------------------------------------------------------
// One-pass scatter: pos = rowstart[dst] + rank. (R1-verified)
// ---------------------------------------------------------------------------
__global__ __launch_bounds__(256) void k_scatter(
    const int* __restrict__ ei, const int* __restrict__ rowstart,
    const int* __restrict__ rank, int E, int Etot, int* __restrict__ csr_src) {
  int e = blockIdx.x * 256 + threadIdx.x;
  if (e >= Etot) return;
  int d = (e < E) ? ei[E + e] : (e - E);
  int s = (e < E) ? ei[e] : d;
  csr_src[rowstart[d] + rank[e]] = s;
}

// ---------------------------------------------------------------------------
// Fused GAT agg + bias + ELU + LN, layer 1 (4 heads).
// 16 threads/node, 8 channels/lane, 8-edge unrolled masked main loop
// (8 payload gathers in flight; masked slots clamp to end-1 = guaranteed
// cache hit, weight forced to 0).
// ---------------------------------------------------------------------------
__global__ __launch_bounds__(256) void k_agg1(
    const int* __restrict__ rowstart, const int* __restrict__ csr_src,
    const float* __restrict__ asrc, const float* __restrict__ adst,
    const unsigned short* __restrict__ hb, const float* __restrict__ bias,
    const float* __restrict__ g, const float* __restrict__ beta,
    unsigned short* __restrict__ outb, int N) {
  int d = blockIdx.x * 16 + (threadIdx.x >> 4);
  if (d >= N) return;
  int lane = threadIdx.x & 15;
  int c0 = lane << 3;  // 8 channels per lane
  int hd = lane >> 2;  // head = c0/32
  float ad = adst[d * HEADS + hd];
  int beg = rowstart[d], end = rowstart[d + 1];
  float a0 = 0.f, a1 = 0.f, a2 = 0.f, a3 = 0.f;
  float a4 = 0.f, a5 = 0.f, a6 = 0.f, a7 = 0.f, wsum = 0.f;
  for (int i = beg; i < end; i += 8) {
    int s[8];
#pragma unroll
    for (int j = 0; j < 8; ++j) {
      int e = i + j;
      s[j] = csr_src[e < end ? e : end - 1];
    }
    float lg[8];
    uint4 p[8];
#pragma unroll
    for (int j = 0; j < 8; ++j) lg[j] = asrc[s[j] * HEADS + hd];
#pragma unroll
    for (int j = 0; j < 8; ++j)
      p[j] = *(const uint4*)(hb + (size_t)s[j] * HID + c0);
    float wv[8];
#pragma unroll
    for (int j = 0; j < 8; ++j) {
      float v = lg[j] + ad;
      v = v < 0.f ? NEG * v : v;
      float ex = __expf(v);
      wv[j] = (i + j < end) ? ex : 0.f;
    }
    wsum += ((wv[0] + wv[1]) + (wv[2] + wv[3])) +
            ((wv[4] + wv[5]) + (wv[6] + wv[7]));
#pragma unroll
    for (int j = 0; j < 8; ++j) {
      a0 += wv[j] * bflo(p[j].x);
      a1 += wv[j] * bfhi(p[j].x);
      a2 += wv[j] * bflo(p[j].y);
      a3 += wv[j] * bfhi(p[j].y);
      a4 += wv[j] * bflo(p[j].z);
      a5 += wv[j] * bfhi(p[j].z);
      a6 += wv[j] * bflo(p[j].w);
      a7 += wv[j] * bfhi(p[j].w);
    }
  }
  float rw = 1.f / wsum;
  float v0 = a0 * rw + bias[c0 + 0];
  float v1 = a1 * rw + bias[c0 + 1];
  float v2 = a2 * rw + bias[c0 + 2];
  float v3 = a3 * rw + bias[c0 + 3];
  float v4 = a4 * rw + bias[c0 + 4];
  float v5 = a5 * rw + bias[c0 + 5];
  float v6 = a6 * rw + bias[c0 + 6];
  float v7 = a7 * rw + bias[c0 + 7];
  v0 = v0 > 0.f ? v0 : (__expf(v0) - 1.f);
  v1 = v1 > 0.f ? v1 : (__expf(v1) - 1.f);
  v2 = v2 > 0.f ? v2 : (__expf(v2) - 1.f);
  v3 = v3 > 0.f ? v3 : (__expf(v3) - 1.f);
  v4 = v4 > 0.f ? v4 : (__expf(v4) - 1.f);
  v5 = v5 > 0.f ? v5 : (__expf(v5) - 1.f);
  v6 = v6 > 0.f ? v6 : (__expf(v6) - 1.f);
  v7 = v7 > 0.f ? v7 : (__expf(v7) - 1.f);
  float s1 = ((v0 + v1) + (v2 + v3)) + ((v4 + v5) + (v6 + v7));
  float s2 = ((v0 * v0 + v1 * v1) + (v2 * v2 + v3 * v3)) +
             ((v4 * v4 + v5 * v5) + (v6 * v6 + v7 * v7));
#pragma unroll
  for (int o = 8; o > 0; o >>= 1) {
    s1 += __shfl_down(s1, o, 16);
    s2 += __shfl_down(s2, o, 16);
  }
  s1 = __shfl(s1, 0, 16);
  s2 = __shfl(s2, 0, 16);
  float mu = s1 * (1.f / HID);
  float var = s2 * (1.f / HID) - mu * mu;
  float inv = rsqrtf(var + LN_EPS);
  ushort4 q0, q1;
  q0.x = f2bf((v0 - mu) * inv * g[c0 + 0] + beta[c0 + 0]);
  q0.y = f2bf((v1 - mu) * inv * g[c0 + 1] + beta[c0 + 1]);
  q0.z = f2bf((v2 - mu) * inv * g[c0 + 2] + beta[c0 + 2]);
  q0.w = f2bf((v3 - mu) * inv * g[c0 + 3] + beta[c0 + 3]);
  q1.x = f2bf((v4 - mu) * inv * g[c0 + 4] + beta[c0 + 4]);
  q1.y = f2bf((v5 - mu) * inv * g[c0 + 5] + beta[c0 + 5]);
  q1.z = f2bf((v6 - mu) * inv * g[c0 + 6] + beta[c0 + 6]);
  q1.w = f2bf((v7 - mu) * inv * g[c0 + 7] + beta[c0 + 7]);
  *(ushort4*)(outb + (size_t)d * HID + c0) = q0;
  *(ushort4*)(outb + (size_t)d * HID + c0 + 4) = q1;
}

// ---------------------------------------------------------------------------
// Fused GAT agg + bias + ELU + LN, layer 2 (1 head). Same 8-edge structure.
// ---------------------------------------------------------------------------
__global__ __launch_bounds__(256) void k_agg2(
    const int* __restrict__ rowstart, const int* __restrict__ csr_src,
    const float* __restrict__ asrc, const float* __restrict__ adst,
    const unsigned short* __restrict__ hb, const float* __restrict__ bias,
    const float* __restrict__ g, const float* __restrict__ beta,
    float* __restrict__ out, int N) {
  int d = blockIdx.x * 16 + (threadIdx.x >> 4);
  if (d >= N) return;
  int lane = threadIdx.x & 15;
  int c0 = lane << 3;
  float ad = adst[d];
  int beg = rowstart[d], end = rowstart[d + 1];
  float a0 = 0.f, a1 = 0.f, a2 = 0.f, a3 = 0.f;
  float a4 = 0.f, a5 = 0.f, a6 = 0.f, a7 = 0.f, wsum = 0.f;
  for (int i = beg; i < end; i += 8) {
    int s[8];
#pragma unroll
    for (int j = 0; j < 8; ++j) {
      int e = i + j;
      s[j] = csr_src[e < end ? e : end - 1];
    }
    float lg[8];
    uint4 p[8];
#pragma unroll
    for (int j = 0; j < 8; ++j) lg[j] = asrc[s[j]];
#pragma unroll
    for (int j = 0; j < 8; ++j)
      p[j] = *(const uint4*)(hb + (size_t)s[j] * HID + c0);
    float wv[8];
#pragma unroll
    for (int j = 0; j < 8; ++j) {
      float v = lg[j] + ad;
      v = v < 0.f ? NEG * v : v;
      float ex = __expf(v);
      wv[j] = (i + j < end) ? ex : 0.f;
    }
    wsum += ((wv[0] + wv[1]) + (wv[2] + wv[3])) +
            ((wv[4] + wv[5]) + (wv[6] + wv[7]));
#pragma unroll
    for (int j = 0; j < 8; ++j) {
      a0 += wv[j] * bflo(p[j].x);
      a1 += wv[j] * bfhi(p[j].x);
      a2 += wv[j] * bflo(p[j].y);
      a3 += wv[j] * bfhi(p[j].y);
      a4 += wv[j] * bflo(p[j].z);
      a5 += wv[j] * bfhi(p[j].z);
      a6 += wv[j] * bflo(p[j].w);
      a7 += wv[j] * bfhi(p[j].w);
    }
  }
  float rw = 1.f / wsum;
  float v0 = a0 * rw + bias[c0 + 0];
  float v1 = a1 * rw + bias[c0 + 1];
  float v2 = a2 * rw + bias[c0 + 2];
  float v3 = a3 * rw + bias[c0 + 3];
  float v4 = a4 * rw + bias[c0 + 4];
  float v5 = a5 * rw + bias[c0 + 5];
  float v6 = a6 * rw + bias[c0 + 6];
  float v7 = a7 * rw + bias[c0 + 7];
  v0 = v0 > 0.f ? v0 : (__expf(v0) - 1.f);
  v1 = v1 > 0.f ? v1 : (__expf(v1) - 1.f);
  v2 = v2 > 0.f ? v2 : (__expf(v2) - 1.f);
  v3 = v3 > 0.f ? v3 : (__expf(v3) - 1.f);
  v4 = v4 > 0.f ? v4 : (__expf(v4) - 1.f);
  v5 = v5 > 0.f ? v5 : (__expf(v5) - 1.f);
  v6 = v6 > 0.f ? v6 : (__expf(v6) - 1.f);
  v7 = v7 > 0.f ? v7 : (__expf(v7) - 1.f);
  float s1 = ((v0 + v1) + (v2 + v3)) + ((v4 + v5) + (v6 + v7));
  float s2 = ((v0 * v0 + v1 * v1) + (v2 * v2 + v3 * v3)) +
             ((v4 * v4 + v5 * v5) + (v6 * v6 + v7 * v7));
#pragma unroll
  for (int o = 8; o > 0; o >>= 1) {
    s1 += __shfl_down(s1, o, 16);
    s2 += __shfl_down(s2, o, 16);
  }
  s1 = __shfl(s1, 0, 16);
  s2 = __shfl(s2, 0, 16);
  float mu = s1 * (1.f / HID);
  float var = s2 * (1.f / HID) - mu * mu;
  float inv = rsqrtf(var + LN_EPS);
  float4 o0, o1;
  o0.x = (v0 - mu) * inv * g[c0 + 0] + beta[c0 + 0];
  o0.y = (v1 - mu) * inv * g[c0 + 1] + beta[c0 + 1];
  o0.z = (v2 - mu) * inv * g[c0 + 2] + beta[c0 + 2];
  o0.w = (v3 - mu) * inv * g[c0 + 3] + beta[c0 + 3];
  o1.x = (v4 - mu) * inv * g[c0 + 4] + beta[c0 + 4];
  o1.y = (v5 - mu) * inv * g[c0 + 5] + beta[c0 + 5];
  o1.z = (v6 - mu) * inv * g[c0 + 6] + beta[c0 + 6];
  o1.w = (v7 - mu) * inv * g[c0 + 7] + beta[c0 + 7];
  *(float4*)(out + (size_t)d * HID + c0) = o0;
  *(float4*)(out + (size_t)d * HID + c0 + 4) = o1;
}

// ---------------------------------------------------------------------------
// Pack W2 (f32 128x128) into MFMA B-fragment order, bf16 hi+lo. (R1-verified)
// ---------------------------------------------------------------------------
__global__ __launch_bounds__(256) void k_w2pack(
    const float* __restrict__ W2, unsigned short* __restrict__ w2hi,
    unsigned short* __restrict__ w2lo) {
  int idx = blockIdx.x * 256 + threadIdx.x;  // 16384 total
  int i = idx & 7;
  int lane = (idx >> 3) & 63;
  int t = (idx >> 9) & 7;
  int kb = idx >> 12;
  int k = kb * 32 + (lane >> 4) * 8 + i;
  int c = t * 16 + (lane & 15);
  float w = W2[k * HID + c];
  unsigned short hi = f2bf(w);
  float res = w - bf2f(hi);
  w2hi[idx] = hi;
  w2lo[idx] = f2bf(res);
}

// ---------------------------------------------------------------------------
// h2 = x2 @ W2 via MFMA bf16 (W2 = Whi + Wlo split for f32-level accuracy).
// 4 waves/block, 2 A-tiles (32 nodes) per wave: each B-fragment load feeds
// 4 MFMAs. Epilogue reuses one 16-row LDS buffer twice.
// ---------------------------------------------------------------------------
__global__ __launch_bounds__(256) void k_gemm2m(
    const unsigned short* __restrict__ x2b,
    const unsigned short* __restrict__ w2hi,
    const unsigned short* __restrict__ w2lo,
    const float* __restrict__ a_src, const float* __restrict__ a_dst,
    unsigned short* __restrict__ h2b, float* __restrict__ asrc,
    float* __restrict__ adst, int N) {
  __shared__ float cs[4][16][132];
  int w = threadIdx.x >> 6;
  int l = threadIdx.x & 63;
  int n0 = blockIdx.x * 128 + w * 32;
  int m = l & 15;    // A row within tile
  int kg = l >> 4;   // k-group
  int naA = n0 + m;
  if (naA >= N) naA = N - 1;  // clamp loads; garbage rows never stored
  int naB = n0 + 16 + m;
  if (naB >= N) naB = N - 1;
  const unsigned short* xA = x2b + (size_t)naA * HID + kg * 8;
  const unsigned short* xB = x2b + (size_t)naB * HID + kg * 8;
  f32x4 accA[8] = {};
  f32x4 accB[8] = {};
#pragma unroll
  for (int kb = 0; kb < 4; ++kb) {
    bf16x8 aA = *(const bf16x8*)(xA + kb * 32);
    bf16x8 aB = *(const bf16x8*)(xB + kb * 32);
#pragma unroll
    for (int t = 0; t < 8; ++t) {
      bf16x8 bl = *(const bf16x8*)(w2lo + ((kb * 8 + t) * 64 + l) * 8);
      bf16x8 bh = *(const bf16x8*)(w2hi + ((kb * 8 + t) * 64 + l) * 8);
      accA[t] = __builtin_amdgcn_mfma_f32_16x16x32_bf16(aA, bl, accA[t], 0, 0, 0);
      accA[t] = __builtin_amdgcn_mfma_f32_16x16x32_bf16(aA, bh, accA[t], 0, 0, 0);
      accB[t] = __builtin_amdgcn_mfma_f32_16x16x32_bf16(aB, bl, accB[t], 0, 0, 0);
      accB[t] = __builtin_amdgcn_mfma_f32_16x16x32_bf16(aB, bh, accB[t], 0, 0, 0);
    }
  }
  // C/D layout (measured): col = lane&15, row = (lane>>4)*4 + reg.
  auto epilog = [&](const f32x4(&acc)[8], int noff) {
#pragma unroll
    for (int t = 0; t < 8; ++t)
#pragma unroll
      for (int j = 0; j < 4; ++j) cs[w][kg * 4 + j][t * 16 + m] = acc[t][j];
    __syncthreads();
    int r2 = l & 15;
    int q = l >> 4;
    int n = n0 + noff + r2;
    if (n < N) {
      const float* rowp = &cs[w][r2][0];
      float pa = 0.f, pd = 0.f;
#pragma unroll
      for (int j = 0; j < 8; ++j) {
        int cc = q * 32 + j * 4;
        float4 v = *(const float4*)(rowp + cc);
        float4 as = *(const float4*)(a_src + cc);
        float4 av = *(const float4*)(a_dst + cc);
        pa += v.x * as.x + v.y * as.y + v.z * as.z + v.w * as.w;
        pd += v.x * av.x + v.y * av.y + v.z * av.z + v.w * av.w;
        ushort4 ob;
        ob.x = f2bf(v.x);
        ob.y = f2bf(v.y);
        ob.z = f2bf(v.z);
        ob.w = f2bf(v.w);
        *(ushort4*)(h2b + (size_t)n * HID + cc) = ob;
      }
      pa += __shfl_xor(pa, 16, 64);
      pa += __shfl_xor(pa, 32, 64);
      pd += __shfl_xor(pd, 16, 64);
      pd += __shfl_xor(pd, 32, 64);
      if (q == 0) {
        asrc[n] = pa;
        adst[n] = pd;
      }
    }
    __syncthreads();
  };
  epilog(accA, 0);
  epilog(accB, 16);
}

extern "C" void kernel_launch(void* const* d_in, const int* in_sizes, int n_in,
                              void* d_out, int out_size, void* d_ws, size_t ws_size,
                              hipStream_t stream) {
  const float* x      = (const float*)d_in[0];
  const int*   ei     = (const int*)d_in[1];
  const float* W1     = (const float*)d_in[2];
  const float* a_src1 = (const float*)d_in[3];
  const float* a_dst1 = (const float*)d_in[4];
  const float* b1     = (const float*)d_in[5];
  const float* g1     = (const float*)d_in[6];
  const float* beta1  = (const float*)d_in[7];
  const float* W2     = (const float*)d_in[8];
  const float* a_src2 = (const float*)d_in[9];
  const float* a_dst2 = (const float*)d_in[10];
  const float* b2     = (const float*)d_in[11];
  const float* g2     = (const float*)d_in[12];
  const float* beta2  = (const float*)d_in[13];
  float* out = (float*)d_out;

  const int N = in_sizes[0] / IN_CH;
  const int E = in_sizes[1] / 2;
  const int Etot = E + N;
  const int nblk = (N + 255) / 256;

  // workspace layout (all chunks 16B-aligned)
  unsigned short* hb  = (unsigned short*)d_ws;          // h1 bf16 -> h2 bf16
  unsigned short* x2b = hb + (size_t)N * HID;           // x2 bf16
  float* asrc1 = (float*)(x2b + (size_t)N * HID);
  float* adst1 = asrc1 + (size_t)N * HEADS;
  float* asrc2 = adst1 + (size_t)N * HEADS;
  float* adst2 = asrc2 + N;
  int* deg      = (int*)(adst2 + N);
  int* part     = deg + N;
  int* rowstart = part + N;           // [N+1] padded to N+4
  int* aux      = rowstart + N + 4;   // [<=1024]
  int* csr_src  = aux + 1024;         // [Etot]
  int* rank     = csr_src + Etot;     // [Etot]
  unsigned short* w2hi = (unsigned short*)(rank + Etot);  // [16384]
  unsigned short* w2lo = w2hi + 16384;                    // [16384]

  // ---- W2 fragment pack (independent of everything else) ----
  k_w2pack<<<64, 256, 0, stream>>>(W2, w2hi, w2lo);

  // ---- CSR build (shared by both layers) ----
  hipMemsetAsync(deg, 0, (size_t)N * sizeof(int), stream);
  k_deg<<<(Etot + 255) / 256, 256, 0, stream>>>(ei, E, Etot, deg, rank);
  k_scan1<<<nblk, 256, 0, stream>>>(deg, part, aux, N);
  k_scan2<<<1, 512, 0, stream>>>(aux, nblk);
  k_scan3<<<nblk, 256, 0, stream>>>(part, aux, rowstart, N, Etot);
  k_scatter<<<(Etot + 255) / 256, 256, 0, stream>>>(ei, rowstart, rank, E, Etot,
                                                    csr_src);

  // ---- Layer 1 ----
  k_gemm1<<<N, 128, 0, stream>>>(x, W1, a_src1, a_dst1, hb, asrc1, adst1, N);
  k_agg1<<<(N + 15) / 16, 256, 0, stream>>>(rowstart, csr_src, asrc1, adst1, hb,
                                            b1, g1, beta1, x2b, N);

  // ---- Layer 2 ----  (h2 bf16 reuses hb; h1 dead after agg1)
  k_gemm2m<<<(N + 127) / 128, 256, 0, stream>>>(x2b, w2hi, w2lo, a_src2,
                                                a_dst2, hb, asrc2, adst2, N);
  k_agg2<<<(N + 15) / 16, 256, 0, stream>>>(rowstart, csr_src, asrc2, adst2, hb,
                                            b2, g2, beta2, out, N);
}

// Round 4
// 397.999 us; speedup vs baseline: 1.0185x; 1.0185x over previous
//
#include <hip/hip_runtime.h>

#define IN_CH 16
#define HID 128
#define HEADS 4
#define NEG 0.2f
#define LN_EPS 1e-5f

typedef short bf16x8 __attribute__((ext_vector_type(8)));
typedef float f32x4 __attribute__((ext_vector_type(4)));

__device__ __forceinline__ float bf2f(unsigned short u) {
  return __uint_as_float(((unsigned)u) << 16);
}
__device__ __forceinline__ float bflo(unsigned u) {
  return __uint_as_float(u << 16);
}
__device__ __forceinline__ float bfhi(unsigned u) {
  return __uint_as_float(u & 0xffff0000u);
}
__device__ __forceinline__ unsigned short f2bf(float f) {
  unsigned u = __float_as_uint(f);
  unsigned r = (u + 0x7fffu + ((u >> 16) & 1u)) >> 16;  // RNE
  return (unsigned short)r;
}
// sign-extended byte -> float. sh in {0,8,16,24}.
__device__ __forceinline__ float sb(unsigned v, int sh) {
  return (float)((int)(v << (24 - sh)) >> 24);
}

// ---------------------------------------------------------------------------
// h1 = x @ W1 (N x 16 @ 16 x 128) -> int8 (per-node scale), fused per-head
// attention logits. rec[n*8] = {asrc[0..3], scale, pad} (one 32B line).
// ---------------------------------------------------------------------------
__global__ __launch_bounds__(128) void k_gemm1(
    const float* __restrict__ x, const float* __restrict__ W1,
    const float* __restrict__ a_src, const float* __restrict__ a_dst,
    signed char* __restrict__ hq, float* __restrict__ rec,
    float* __restrict__ adst, int N) {
  int n = blockIdx.x;
  int c = threadIdx.x;
  __shared__ float xs[IN_CH];
  __shared__ float wmax[2];
  if (c < IN_CH) xs[c] = x[n * IN_CH + c];
  __syncthreads();
  float acc = 0.f;
#pragma unroll
  for (int k = 0; k < IN_CH; ++k) acc += xs[k] * W1[k * HID + c];
  // attention logits (per 32-lane head group)
  float av = acc * a_src[c];
  float dv = acc * a_dst[c];
#pragma unroll
  for (int o = 16; o > 0; o >>= 1) {
    av += __shfl_down(av, o, 32);
    dv += __shfl_down(dv, o, 32);
  }
  if ((c & 31) == 0) {
    rec[n * 8 + (c >> 5)] = av;
    adst[n * HEADS + (c >> 5)] = dv;
  }
  // row absmax over 128 threads (2 waves)
  float m = fabsf(acc);
#pragma unroll
  for (int o = 32; o > 0; o >>= 1) m = fmaxf(m, __shfl_xor(m, o, 64));
  if ((c & 63) == 0) wmax[c >> 6] = m;
  __syncthreads();
  float mm = fmaxf(wmax[0], wmax[1]);
  float rs = (mm > 0.f) ? 127.f / mm : 0.f;
  hq[(size_t)n * HID + c] = (signed char)__float2int_rn(acc * rs);
  if (c == 0) rec[n * 8 + 4] = mm * (1.f / 127.f);
}

// ---------------------------------------------------------------------------
// CSR build: degree count + per-edge rank. (R1-verified)
// ---------------------------------------------------------------------------
__global__ __launch_bounds__(256) void k_deg(
    const int* __restrict__ ei, int E, int Etot, int* __restrict__ deg,
    int* __restrict__ rank) {
  int e = blockIdx.x * 256 + threadIdx.x;
  if (e >= Etot) return;
  int d = (e < E) ? ei[E + e] : (e - E);
  rank[e] = atomicAdd(&deg[d], 1);
}

__global__ __launch_bounds__(256) void k_scan1(
    const int* __restrict__ deg, int* __restrict__ part, int* __restrict__ aux,
    int N) {
  int i = blockIdx.x * 256 + threadIdx.x;
  int v = (i < N) ? deg[i] : 0;
  int lane = threadIdx.x & 63, w = threadIdx.x >> 6;
  int inc = v;
#pragma unroll
  for (int o = 1; o < 64; o <<= 1) {
    int t = __shfl_up(inc, o, 64);
    if (lane >= o) inc += t;
  }
  __shared__ int wsum[4];
  if (lane == 63) wsum[w] = inc;
  __syncthreads();
  int woff = 0;
#pragma unroll
  for (int k = 0; k < 4; ++k)
    if (k < w) woff += wsum[k];
  if (i < N) part[i] = woff + inc - v;
  if (threadIdx.x == 255) aux[blockIdx.x] = woff + inc;
}

__global__ __launch_bounds__(512) void k_scan2(int* __restrict__ aux, int nb) {
  int i = threadIdx.x;
  int v = (i < nb) ? aux[i] : 0;
  int lane = i & 63, w = i >> 6;
  int inc = v;
#pragma unroll
  for (int o = 1; o < 64; o <<= 1) {
    int t = __shfl_up(inc, o, 64);
    if (lane >= o) inc += t;
  }
  __shared__ int wsum[8];
  if (lane == 63) wsum[w] = inc;
  __syncthreads();
  int woff = 0;
#pragma unroll
  for (int k = 0; k < 8; ++k)
    if (k < w) woff += wsum[k];
  if (i < nb) aux[i] = woff + inc - v;
}

__global__ __launch_bounds__(256) void k_scan3(
    const int* __restrict__ part, const int* __restrict__ aux,
    int* __restrict__ rowstart, int N, int Etot) {
  int i = blockIdx.x * 256 + threadIdx.x;
  if (i < N) rowstart[i] = part[i] + aux[blockIdx.x];
  if (i == 0) rowstart[N] = Etot;
}

// ---------------------------------------------------------------------------
// One-pass scatter: pos = rowstart[dst] + rank. (R1-verified)
// ---------------------------------------------------------------------------
__global__ __launch_bounds__(256) void k_scatter(
    const int* __restrict__ ei, const int* __restrict__ rowstart,
    const int* __restrict__ rank, int E, int Etot, int* __restrict__ csr_src) {
  int e = blockIdx.x * 256 + threadIdx.x;
  if (e >= Etot) return;
  int d = (e < E) ? ei[E + e] : (e - E);
  int s = (e < E) ? ei[e] : d;
  csr_src[rowstart[d] + rank[e]] = s;
}

// ---------------------------------------------------------------------------
// Fused GAT agg + bias + ELU + LN, layer 1 (4 heads). int8 payload gathers
// (8 B/lane, 1 line/edge) + packed {logits,scale} record (1 line/edge).
// 16 threads/node, 8 channels/lane, 8-edge masked unroll.
// ---------------------------------------------------------------------------
__global__ __launch_bounds__(256) void k_agg1(
    const int* __restrict__ rowstart, const int* __restrict__ csr_src,
    const float* __restrict__ rec, const float* __restrict__ adst,
    const signed char* __restrict__ hq, const float* __restrict__ bias,
    const float* __restrict__ g, const float* __restrict__ beta,
    unsigned short* __restrict__ outb, int N) {
  int d = blockIdx.x * 16 + (threadIdx.x >> 4);
  if (d >= N) return;
  int lane = threadIdx.x & 15;
  int c0 = lane << 3;  // 8 channels per lane
  int hd = lane >> 2;  // head = c0/32
  float ad = adst[d * HEADS + hd];
  int beg = rowstart[d], end = rowstart[d + 1];
  float a0 = 0.f, a1 = 0.f, a2 = 0.f, a3 = 0.f;
  float a4 = 0.f, a5 = 0.f, a6 = 0.f, a7 = 0.f, wsum = 0.f;
  for (int i = beg; i < end; i += 8) {
    int s[8];
#pragma unroll
    for (int j = 0; j < 8; ++j) {
      int e = i + j;
      s[j] = csr_src[e < end ? e : end - 1];
    }
    float lg[8], sc[8];
    uint2 p[8];
#pragma unroll
    for (int j = 0; j < 8; ++j) {
      lg[j] = rec[s[j] * 8 + hd];
      sc[j] = rec[s[j] * 8 + 4];
    }
#pragma unroll
    for (int j = 0; j < 8; ++j)
      p[j] = *(const uint2*)(hq + (size_t)s[j] * HID + c0);
#pragma unroll
    for (int j = 0; j < 8; ++j) {
      float v = lg[j] + ad;
      v = v < 0.f ? NEG * v : v;
      float ex = __expf(v);
      float w = (i + j < end) ? ex : 0.f;
      wsum += w;
      float ws = w * sc[j];
      a0 += ws * sb(p[j].x, 0);
      a1 += ws * sb(p[j].x, 8);
      a2 += ws * sb(p[j].x, 16);
      a3 += ws * sb(p[j].x, 24);
      a4 += ws * sb(p[j].y, 0);
      a5 += ws * sb(p[j].y, 8);
      a6 += ws * sb(p[j].y, 16);
      a7 += ws * sb(p[j].y, 24);
    }
  }
  float rw = 1.f / wsum;
  float v0 = a0 * rw + bias[c0 + 0];
  float v1 = a1 * rw + bias[c0 + 1];
  float v2 = a2 * rw + bias[c0 + 2];
  float v3 = a3 * rw + bias[c0 + 3];
  float v4 = a4 * rw + bias[c0 + 4];
  float v5 = a5 * rw + bias[c0 + 5];
  float v6 = a6 * rw + bias[c0 + 6];
  float v7 = a7 * rw + bias[c0 + 7];
  v0 = v0 > 0.f ? v0 : (__expf(v0) - 1.f);
  v1 = v1 > 0.f ? v1 : (__expf(v1) - 1.f);
  v2 = v2 > 0.f ? v2 : (__expf(v2) - 1.f);
  v3 = v3 > 0.f ? v3 : (__expf(v3) - 1.f);
  v4 = v4 > 0.f ? v4 : (__expf(v4) - 1.f);
  v5 = v5 > 0.f ? v5 : (__expf(v5) - 1.f);
  v6 = v6 > 0.f ? v6 : (__expf(v6) - 1.f);
  v7 = v7 > 0.f ? v7 : (__expf(v7) - 1.f);
  float s1 = ((v0 + v1) + (v2 + v3)) + ((v4 + v5) + (v6 + v7));
  float s2 = ((v0 * v0 + v1 * v1) + (v2 * v2 + v3 * v3)) +
             ((v4 * v4 + v5 * v5) + (v6 * v6 + v7 * v7));
#pragma unroll
  for (int o = 8; o > 0; o >>= 1) {
    s1 += __shfl_down(s1, o, 16);
    s2 += __shfl_down(s2, o, 16);
  }
  s1 = __shfl(s1, 0, 16);
  s2 = __shfl(s2, 0, 16);
  float mu = s1 * (1.f / HID);
  float var = s2 * (1.f / HID) - mu * mu;
  float inv = rsqrtf(var + LN_EPS);
  ushort4 q0, q1;
  q0.x = f2bf((v0 - mu) * inv * g[c0 + 0] + beta[c0 + 0]);
  q0.y = f2bf((v1 - mu) * inv * g[c0 + 1] + beta[c0 + 1]);
  q0.z = f2bf((v2 - mu) * inv * g[c0 + 2] + beta[c0 + 2]);
  q0.w = f2bf((v3 - mu) * inv * g[c0 + 3] + beta[c0 + 3]);
  q1.x = f2bf((v4 - mu) * inv * g[c0 + 4] + beta[c0 + 4]);
  q1.y = f2bf((v5 - mu) * inv * g[c0 + 5] + beta[c0 + 5]);
  q1.z = f2bf((v6 - mu) * inv * g[c0 + 6] + beta[c0 + 6]);
  q1.w = f2bf((v7 - mu) * inv * g[c0 + 7] + beta[c0 + 7]);
  *(ushort4*)(outb + (size_t)d * HID + c0) = q0;
  *(ushort4*)(outb + (size_t)d * HID + c0 + 4) = q1;
}

// ---------------------------------------------------------------------------
// Fused GAT agg + bias + ELU + LN, layer 2 (1 head). bf16 payload.
// (R3-verified, unchanged)
// ---------------------------------------------------------------------------
__global__ __launch_bounds__(256) void k_agg2(
    const int* __restrict__ rowstart, const int* __restrict__ csr_src,
    const float* __restrict__ asrc, const float* __restrict__ adst,
    const unsigned short* __restrict__ hb, const float* __restrict__ bias,
    const float* __restrict__ g, const float* __restrict__ beta,
    float* __restrict__ out, int N) {
  int d = blockIdx.x * 16 + (threadIdx.x >> 4);
  if (d >= N) return;
  int lane = threadIdx.x & 15;
  int c0 = lane << 3;
  float ad = adst[d];
  int beg = rowstart[d], end = rowstart[d + 1];
  float a0 = 0.f, a1 = 0.f, a2 = 0.f, a3 = 0.f;
  float a4 = 0.f, a5 = 0.f, a6 = 0.f, a7 = 0.f, wsum = 0.f;
  for (int i = beg; i < end; i += 8) {
    int s[8];
#pragma unroll
    for (int j = 0; j < 8; ++j) {
      int e = i + j;
      s[j] = csr_src[e < end ? e : end - 1];
    }
    float lg[8];
    uint4 p[8];
#pragma unroll
    for (int j = 0; j < 8; ++j) lg[j] = asrc[s[j]];
#pragma unroll
    for (int j = 0; j < 8; ++j)
      p[j] = *(const uint4*)(hb + (size_t)s[j] * HID + c0);
    float wv[8];
#pragma unroll
    for (int j = 0; j < 8; ++j) {
      float v = lg[j] + ad;
      v = v < 0.f ? NEG * v : v;
      float ex = __expf(v);
      wv[j] = (i + j < end) ? ex : 0.f;
    }
    wsum += ((wv[0] + wv[1]) + (wv[2] + wv[3])) +
            ((wv[4] + wv[5]) + (wv[6] + wv[7]));
#pragma unroll
    for (int j = 0; j < 8; ++j) {
      a0 += wv[j] * bflo(p[j].x);
      a1 += wv[j] * bfhi(p[j].x);
      a2 += wv[j] * bflo(p[j].y);
      a3 += wv[j] * bfhi(p[j].y);
      a4 += wv[j] * bflo(p[j].z);
      a5 += wv[j] * bfhi(p[j].z);
      a6 += wv[j] * bflo(p[j].w);
      a7 += wv[j] * bfhi(p[j].w);
    }
  }
  float rw = 1.f / wsum;
  float v0 = a0 * rw + bias[c0 + 0];
  float v1 = a1 * rw + bias[c0 + 1];
  float v2 = a2 * rw + bias[c0 + 2];
  float v3 = a3 * rw + bias[c0 + 3];
  float v4 = a4 * rw + bias[c0 + 4];
  float v5 = a5 * rw + bias[c0 + 5];
  float v6 = a6 * rw + bias[c0 + 6];
  float v7 = a7 * rw + bias[c0 + 7];
  v0 = v0 > 0.f ? v0 : (__expf(v0) - 1.f);
  v1 = v1 > 0.f ? v1 : (__expf(v1) - 1.f);
  v2 = v2 > 0.f ? v2 : (__expf(v2) - 1.f);
  v3 = v3 > 0.f ? v3 : (__expf(v3) - 1.f);
  v4 = v4 > 0.f ? v4 : (__expf(v4) - 1.f);
  v5 = v5 > 0.f ? v5 : (__expf(v5) - 1.f);
  v6 = v6 > 0.f ? v6 : (__expf(v6) - 1.f);
  v7 = v7 > 0.f ? v7 : (__expf(v7) - 1.f);
  float s1 = ((v0 + v1) + (v2 + v3)) + ((v4 + v5) + (v6 + v7));
  float s2 = ((v0 * v0 + v1 * v1) + (v2 * v2 + v3 * v3)) +
             ((v4 * v4 + v5 * v5) + (v6 * v6 + v7 * v7));
#pragma unroll
  for (int o = 8; o > 0; o >>= 1) {
    s1 += __shfl_down(s1, o, 16);
    s2 += __shfl_down(s2, o, 16);
  }
  s1 = __shfl(s1, 0, 16);
  s2 = __shfl(s2, 0, 16);
  float mu = s1 * (1.f / HID);
  float var = s2 * (1.f / HID) - mu * mu;
  float inv = rsqrtf(var + LN_EPS);
  float4 o0, o1;
  o0.x = (v0 - mu) * inv * g[c0 + 0] + beta[c0 + 0];
  o0.y = (v1 - mu) * inv * g[c0 + 1] + beta[c0 + 1];
  o0.z = (v2 - mu) * inv * g[c0 + 2] + beta[c0 + 2];
  o0.w = (v3 - mu) * inv * g[c0 + 3] + beta[c0 + 3];
  o1.x = (v4 - mu) * inv * g[c0 + 4] + beta[c0 + 4];
  o1.y = (v5 - mu) * inv * g[c0 + 5] + beta[c0 + 5];
  o1.z = (v6 - mu) * inv * g[c0 + 6] + beta[c0 + 6];
  o1.w = (v7 - mu) * inv * g[c0 + 7] + beta[c0 + 7];
  *(float4*)(out + (size_t)d * HID + c0) = o0;
  *(float4*)(out + (size_t)d * HID + c0 + 4) = o1;
}

// ---------------------------------------------------------------------------
// Pack W2 (f32 128x128) into MFMA B-fragment order, bf16 hi+lo. (R1-verified)
// ---------------------------------------------------------------------------
__global__ __launch_bounds__(256) void k_w2pack(
    const float* __restrict__ W2, unsigned short* __restrict__ w2hi,
    unsigned short* __restrict__ w2lo) {
  int idx = blockIdx.x * 256 + threadIdx.x;  // 16384 total
  int i = idx & 7;
  int lane = (idx >> 3) & 63;
  int t = (idx >> 9) & 7;
  int kb = idx >> 12;
  int k = kb * 32 + (lane >> 4) * 8 + i;
  int c = t * 16 + (lane & 15);
  float w = W2[k * HID + c];
  unsigned short hi = f2bf(w);
  float res = w - bf2f(hi);
  w2hi[idx] = hi;
  w2lo[idx] = f2bf(res);
}

// ---------------------------------------------------------------------------
// h2 = x2 @ W2 via MFMA bf16 (W2 = Whi + Wlo split). (R3-verified, unchanged)
// ---------------------------------------------------------------------------
__global__ __launch_bounds__(256) void k_gemm2m(
    const unsigned short* __restrict__ x2b,
    const unsigned short* __restrict__ w2hi,
    const unsigned short* __restrict__ w2lo,
    const float* __restrict__ a_src, const float* __restrict__ a_dst,
    unsigned short* __restrict__ h2b, float* __restrict__ asrc,
    float* __restrict__ adst, int N) {
  __shared__ float cs[4][16][132];
  int w = threadIdx.x >> 6;
  int l = threadIdx.x & 63;
  int n0 = blockIdx.x * 128 + w * 32;
  int m = l & 15;    // A row within tile
  int kg = l >> 4;   // k-group
  int naA = n0 + m;
  if (naA >= N) naA = N - 1;  // clamp loads; garbage rows never stored
  int naB = n0 + 16 + m;
  if (naB >= N) naB = N - 1;
  const unsigned short* xA = x2b + (size_t)naA * HID + kg * 8;
  const unsigned short* xB = x2b + (size_t)naB * HID + kg * 8;
  f32x4 accA[8] = {};
  f32x4 accB[8] = {};
#pragma unroll
  for (int kb = 0; kb < 4; ++kb) {
    bf16x8 aA = *(const bf16x8*)(xA + kb * 32);
    bf16x8 aB = *(const bf16x8*)(xB + kb * 32);
#pragma unroll
    for (int t = 0; t < 8; ++t) {
      bf16x8 bl = *(const bf16x8*)(w2lo + ((kb * 8 + t) * 64 + l) * 8);
      bf16x8 bh = *(const bf16x8*)(w2hi + ((kb * 8 + t) * 64 + l) * 8);
      accA[t] = __builtin_amdgcn_mfma_f32_16x16x32_bf16(aA, bl, accA[t], 0, 0, 0);
      accA[t] = __builtin_amdgcn_mfma_f32_16x16x32_bf16(aA, bh, accA[t], 0, 0, 0);
      accB[t] = __builtin_amdgcn_mfma_f32_16x16x32_bf16(aB, bl, accB[t], 0, 0, 0);
      accB[t] = __builtin_amdgcn_mfma_f32_16x16x32_bf16(aB, bh, accB[t], 0, 0, 0);
    }
  }
  // C/D layout (measured): col = lane&15, row = (lane>>4)*4 + reg.
  auto epilog = [&](const f32x4(&acc)[8], int noff) {
#pragma unroll
    for (int t = 0; t < 8; ++t)
#pragma unroll
      for (int j = 0; j < 4; ++j) cs[w][kg * 4 + j][t * 16 + m] = acc[t][j];
    __syncthreads();
    int r2 = l & 15;
    int q = l >> 4;
    int n = n0 + noff + r2;
    if (n < N) {
      const float* rowp = &cs[w][r2][0];
      float pa = 0.f, pd = 0.f;
#pragma unroll
      for (int j = 0; j < 8; ++j) {
        int cc = q * 32 + j * 4;
        float4 v = *(const float4*)(rowp + cc);
        float4 as = *(const float4*)(a_src + cc);
        float4 av = *(const float4*)(a_dst + cc);
        pa += v.x * as.x + v.y * as.y + v.z * as.z + v.w * as.w;
        pd += v.x * av.x + v.y * av.y + v.z * av.z + v.w * av.w;
        ushort4 ob;
        ob.x = f2bf(v.x);
        ob.y = f2bf(v.y);
        ob.z = f2bf(v.z);
        ob.w = f2bf(v.w);
        *(ushort4*)(h2b + (size_t)n * HID + cc) = ob;
      }
      pa += __shfl_xor(pa, 16, 64);
      pa += __shfl_xor(pa, 32, 64);
      pd += __shfl_xor(pd, 16, 64);
      pd += __shfl_xor(pd, 32, 64);
      if (q == 0) {
        asrc[n] = pa;
        adst[n] = pd;
      }
    }
    __syncthreads();
  };
  epilog(accA, 0);
  epilog(accB, 16);
}

extern "C" void kernel_launch(void* const* d_in, const int* in_sizes, int n_in,
                              void* d_out, int out_size, void* d_ws, size_t ws_size,
                              hipStream_t stream) {
  const float* x      = (const float*)d_in[0];
  const int*   ei     = (const int*)d_in[1];
  const float* W1     = (const float*)d_in[2];
  const float* a_src1 = (const float*)d_in[3];
  const float* a_dst1 = (const float*)d_in[4];
  const float* b1     = (const float*)d_in[5];
  const float* g1     = (const float*)d_in[6];
  const float* beta1  = (const float*)d_in[7];
  const float* W2     = (const float*)d_in[8];
  const float* a_src2 = (const float*)d_in[9];
  const float* a_dst2 = (const float*)d_in[10];
  const float* b2     = (const float*)d_in[11];
  const float* g2     = (const float*)d_in[12];
  const float* beta2  = (const float*)d_in[13];
  float* out = (float*)d_out;

  const int N = in_sizes[0] / IN_CH;
  const int E = in_sizes[1] / 2;
  const int Etot = E + N;
  const int nblk = (N + 255) / 256;

  // workspace layout (all chunks 16B-aligned)
  // U region: hq (int8 N*HID) + rec (N*8 f32) while layer 1 lives;
  // h2b (bf16 N*HID) overlays it for layer 2 (hq/rec dead after agg1... rec
  // dead after agg1; hq dead after agg1; h2b written in gemm2m).
  unsigned char* U = (unsigned char*)d_ws;
  signed char* hq = (signed char*)U;                      // N*HID int8
  float* rec = (float*)(U + (size_t)N * HID);             // N*8 f32
  unsigned short* h2b = (unsigned short*)U;               // N*HID bf16 (layer2)
  unsigned short* x2b =
      (unsigned short*)(U + (size_t)N * HID + (size_t)N * 32);  // N*HID bf16
  float* adst1 = (float*)(x2b + (size_t)N * HID);
  float* asrc2 = adst1 + (size_t)N * HEADS;
  float* adst2 = asrc2 + N;
  int* deg      = (int*)(adst2 + N);
  int* part     = deg + N;
  int* rowstart = part + N;           // [N+1] padded to N+4
  int* aux      = rowstart + N + 4;   // [<=1024]
  int* csr_src  = aux + 1024;         // [Etot]
  int* rank     = csr_src + Etot;     // [Etot]
  unsigned short* w2hi = (unsigned short*)(rank + Etot);  // [16384]
  unsigned short* w2lo = w2hi + 16384;                    // [16384]

  // ---- W2 fragment pack (independent of everything else) ----
  k_w2pack<<<64, 256, 0, stream>>>(W2, w2hi, w2lo);

  // ---- CSR build (shared by both layers) ----
  hipMemsetAsync(deg, 0, (size_t)N * sizeof(int), stream);
  k_deg<<<(Etot + 255) / 256, 256, 0, stream>>>(ei, E, Etot, deg, rank);
  k_scan1<<<nblk, 256, 0, stream>>>(deg, part, aux, N);
  k_scan2<<<1, 512, 0, stream>>>(aux, nblk);
  k_scan3<<<nblk, 256, 0, stream>>>(part, aux, rowstart, N, Etot);
  k_scatter<<<(Etot + 255) / 256, 256, 0, stream>>>(ei, rowstart, rank, E, Etot,
                                                    csr_src);

  // ---- Layer 1 ----
  k_gemm1<<<N, 128, 0, stream>>>(x, W1, a_src1, a_dst1, hq, rec, adst1, N);
  k_agg1<<<(N + 15) / 16, 256, 0, stream>>>(rowstart, csr_src, rec, adst1, hq,
                                            b1, g1, beta1, x2b, N);

  // ---- Layer 2 ----  (h2b overlays hq/rec; both dead after agg1)
  k_gemm2m<<<(N + 127) / 128, 256, 0, stream>>>(x2b, w2hi, w2lo, a_src2,
                                                a_dst2, h2b, asrc2, adst2, N);
  k_agg2<<<(N + 15) / 16, 256, 0, stream>>>(rowstart, csr_src, asrc2, adst2,
                                            h2b, b2, g2, beta2, out, N);
}

// Round 5
// 357.369 us; speedup vs baseline: 1.1343x; 1.1137x over previous
//
#include <hip/hip_runtime.h>

#define IN_CH 16
#define HID 128
#define HEADS 4
#define NEG 0.2f
#define LN_EPS 1e-5f
#define BCAP 8192  // max edges per 256-node bucket (mean ~4400, +55 sigma)

typedef short bf16x8 __attribute__((ext_vector_type(8)));
typedef float f32x4 __attribute__((ext_vector_type(4)));

__device__ __forceinline__ float bf2f(unsigned short u) {
  return __uint_as_float(((unsigned)u) << 16);
}
__device__ __forceinline__ float bflo(unsigned u) {
  return __uint_as_float(u << 16);
}
__device__ __forceinline__ float bfhi(unsigned u) {
  return __uint_as_float(u & 0xffff0000u);
}
__device__ __forceinline__ unsigned short f2bf(float f) {
  unsigned u = __float_as_uint(f);
  unsigned r = (u + 0x7fffu + ((u >> 16) & 1u)) >> 16;  // RNE
  return (unsigned short)r;
}
// sign-extended byte -> float. sh in {0,8,16,24}.
__device__ __forceinline__ float sb(unsigned v, int sh) {
  return (float)((int)(v << (24 - sh)) >> 24);
}

// ---------------------------------------------------------------------------
// h1 = x @ W1 -> int8 (per-node scale), fused attention logits.
// rec[n*8] = {asrc[0..3], scale, pad}. (R4-verified)
// ---------------------------------------------------------------------------
__global__ __launch_bounds__(128) void k_gemm1(
    const float* __restrict__ x, const float* __restrict__ W1,
    const float* __restrict__ a_src, const float* __restrict__ a_dst,
    signed char* __restrict__ hq, float* __restrict__ rec,
    float* __restrict__ adst, int N) {
  int n = blockIdx.x;
  int c = threadIdx.x;
  __shared__ float xs[IN_CH];
  __shared__ float wmax[2];
  if (c < IN_CH) xs[c] = x[n * IN_CH + c];
  __syncthreads();
  float acc = 0.f;
#pragma unroll
  for (int k = 0; k < IN_CH; ++k) acc += xs[k] * W1[k * HID + c];
  float av = acc * a_src[c];
  float dv = acc * a_dst[c];
#pragma unroll
  for (int o = 16; o > 0; o >>= 1) {
    av += __shfl_down(av, o, 32);
    dv += __shfl_down(dv, o, 32);
  }
  if ((c & 31) == 0) {
    rec[n * 8 + (c >> 5)] = av;
    adst[n * HEADS + (c >> 5)] = dv;
  }
  float m = fabsf(acc);
#pragma unroll
  for (int o = 32; o > 0; o >>= 1) m = fmaxf(m, __shfl_xor(m, o, 64));
  if ((c & 63) == 0) wmax[c >> 6] = m;
  __syncthreads();
  float mm = fmaxf(wmax[0], wmax[1]);
  float rs = (mm > 0.f) ? 127.f / mm : 0.f;
  hq[(size_t)n * HID + c] = (signed char)__float2int_rn(acc * rs);
  if (c == 0) rec[n * 8 + 4] = mm * (1.f / 127.f);
}

// ---------------------------------------------------------------------------
// CSR build, pass A: per-(bucket, block) histogram. bucket = dst >> 8.
// 8192 edges/block, LDS-only atomics.
// ---------------------------------------------------------------------------
__global__ __launch_bounds__(256) void k_hist(
    const int* __restrict__ ei, int E, int Etot, int NBK, int NBLK,
    int* __restrict__ bcnt) {
  __shared__ int lh[512];
  int blk = blockIdx.x;
  for (int i = threadIdx.x; i < 512; i += 256) lh[i] = 0;
  __syncthreads();
  int s0 = blk * 8192, s1 = min(s0 + 8192, Etot);
  for (int e = s0 + threadIdx.x; e < s1; e += 256) {
    int d = (e < E) ? ei[E + e] : (e - E);
    atomicAdd(&lh[d >> 8], 1);
  }
  __syncthreads();
  for (int i = threadIdx.x; i < NBK; i += 256) bcnt[i * NBLK + blk] = lh[i];
}

__global__ __launch_bounds__(256) void k_scan1(
    const int* __restrict__ deg, int* __restrict__ part, int* __restrict__ aux,
    int N) {
  int i = blockIdx.x * 256 + threadIdx.x;
  int v = (i < N) ? deg[i] : 0;
  int lane = threadIdx.x & 63, w = threadIdx.x >> 6;
  int inc = v;
#pragma unroll
  for (int o = 1; o < 64; o <<= 1) {
    int t = __shfl_up(inc, o, 64);
    if (lane >= o) inc += t;
  }
  __shared__ int wsum[4];
  if (lane == 63) wsum[w] = inc;
  __syncthreads();
  int woff = 0;
#pragma unroll
  for (int k = 0; k < 4; ++k)
    if (k < w) woff += wsum[k];
  if (i < N) part[i] = woff + inc - v;
  if (threadIdx.x == 255) aux[blockIdx.x] = woff + inc;
}

__global__ __launch_bounds__(512) void k_scan2(int* __restrict__ aux, int nb) {
  int i = threadIdx.x;
  int v = (i < nb) ? aux[i] : 0;
  int lane = i & 63, w = i >> 6;
  int inc = v;
#pragma unroll
  for (int o = 1; o < 64; o <<= 1) {
    int t = __shfl_up(inc, o, 64);
    if (lane >= o) inc += t;
  }
  __shared__ int wsum[8];
  if (lane == 63) wsum[w] = inc;
  __syncthreads();
  int woff = 0;
#pragma unroll
  for (int k = 0; k < 8; ++k)
    if (k < w) woff += wsum[k];
  if (i < nb) aux[i] = woff + inc - v;
}

__global__ __launch_bounds__(256) void k_scan3g(
    const int* __restrict__ part, const int* __restrict__ aux,
    int* __restrict__ out, int M) {
  int i = blockIdx.x * 256 + threadIdx.x;
  if (i < M) out[i] = part[i] + aux[blockIdx.x];
}

// ---------------------------------------------------------------------------
// CSR build, pass C: place edges into bucket-contiguous storage.
// bbuf value = (src << 8) | (dst & 255). LDS cursors (no global atomics).
// ---------------------------------------------------------------------------
__global__ __launch_bounds__(256) void k_bucket(
    const int* __restrict__ ei, const int* __restrict__ bpre, int E, int Etot,
    int NBK, int NBLK, unsigned* __restrict__ bbuf) {
  __shared__ int lc[512];
  int blk = blockIdx.x;
  for (int i = threadIdx.x; i < NBK; i += 256) lc[i] = bpre[i * NBLK + blk];
  __syncthreads();
  int s0 = blk * 8192, s1 = min(s0 + 8192, Etot);
  for (int e = s0 + threadIdx.x; e < s1; e += 256) {
    int d = (e < E) ? ei[E + e] : (e - E);
    int s = (e < E) ? ei[e] : d;
    int pos = atomicAdd(&lc[d >> 8], 1);
    bbuf[pos] = ((unsigned)s << 8) | (unsigned)(d & 255);
  }
}

// ---------------------------------------------------------------------------
// CSR build, pass D: one block per bucket. LDS degree count over 256 local
// nodes -> LDS scan -> rowstart; LDS reorder -> coalesced csr_src write.
// ---------------------------------------------------------------------------
__global__ __launch_bounds__(256) void k_build(
    const unsigned* __restrict__ bbuf, const int* __restrict__ bpre,
    int* __restrict__ rowstart, int* __restrict__ csr_src, int N, int Etot,
    int NBK, int NBLK) {
  __shared__ int ldeg[256], lcur[256], wsum[4];
  __shared__ int lout[BCAP];
  int bin = blockIdx.x;
  int base = bpre[bin * NBLK];
  int next = (bin + 1 < NBK) ? bpre[(bin + 1) * NBLK] : Etot;
  int cnt = next - base;
  if (cnt > BCAP) cnt = BCAP;  // never triggers (+55 sigma margin)
  int tid = threadIdx.x;
  ldeg[tid] = 0;
  __syncthreads();
  for (int i = tid; i < cnt; i += 256)
    atomicAdd(&ldeg[bbuf[base + i] & 255u], 1);
  __syncthreads();
  // exclusive scan of ldeg over 256 bins (4 waves)
  int v = ldeg[tid];
  int lane = tid & 63, wv = tid >> 6;
  int inc = v;
#pragma unroll
  for (int o = 1; o < 64; o <<= 1) {
    int t = __shfl_up(inc, o, 64);
    if (lane >= o) inc += t;
  }
  if (lane == 63) wsum[wv] = inc;
  __syncthreads();
  int woff = 0;
#pragma unroll
  for (int k = 0; k < 4; ++k)
    if (k < wv) woff += wsum[k];
  int pre = woff + inc - v;  // exclusive prefix
  int node = bin * 256 + tid;
  if (node < N) rowstart[node] = base + pre;
  lcur[tid] = pre;
  __syncthreads();
  for (int i = tid; i < cnt; i += 256) {
    unsigned u = bbuf[base + i];
    int p = atomicAdd(&lcur[u & 255u], 1);
    lout[p] = (int)(u >> 8);
  }
  __syncthreads();
  for (int i = tid; i < cnt; i += 256) csr_src[base + i] = lout[i];
  if (bin == 0 && tid == 0) rowstart[N] = Etot;
}

// ---------------------------------------------------------------------------
// Fused GAT agg + bias + ELU + LN, layer 1 (4 heads). int8 payload.
// (R4-verified)
// ---------------------------------------------------------------------------
__global__ __launch_bounds__(256) void k_agg1(
    const int* __restrict__ rowstart, const int* __restrict__ csr_src,
    const float* __restrict__ rec, const float* __restrict__ adst,
    const signed char* __restrict__ hq, const float* __restrict__ bias,
    const float* __restrict__ g, const float* __restrict__ beta,
    unsigned short* __restrict__ outb, int N) {
  int d = blockIdx.x * 16 + (threadIdx.x >> 4);
  if (d >= N) return;
  int lane = threadIdx.x & 15;
  int c0 = lane << 3;  // 8 channels per lane
  int hd = lane >> 2;  // head = c0/32
  float ad = adst[d * HEADS + hd];
  int beg = rowstart[d], end = rowstart[d + 1];
  float a0 = 0.f, a1 = 0.f, a2 = 0.f, a3 = 0.f;
  float a4 = 0.f, a5 = 0.f, a6 = 0.f, a7 = 0.f, wsum = 0.f;
  for (int i = beg; i < end; i += 8) {
    int s[8];
#pragma unroll
    for (int j = 0; j < 8; ++j) {
      int e = i + j;
      s[j] = csr_src[e < end ? e : end - 1];
    }
    float lg[8], sc[8];
    uint2 p[8];
#pragma unroll
    for (int j = 0; j < 8; ++j) {
      lg[j] = rec[s[j] * 8 + hd];
      sc[j] = rec[s[j] * 8 + 4];
    }
#pragma unroll
    for (int j = 0; j < 8; ++j)
      p[j] = *(const uint2*)(hq + (size_t)s[j] * HID + c0);
#pragma unroll
    for (int j = 0; j < 8; ++j) {
      float v = lg[j] + ad;
      v = v < 0.f ? NEG * v : v;
      float ex = __expf(v);
      float w = (i + j < end) ? ex : 0.f;
      wsum += w;
      float ws = w * sc[j];
      a0 += ws * sb(p[j].x, 0);
      a1 += ws * sb(p[j].x, 8);
      a2 += ws * sb(p[j].x, 16);
      a3 += ws * sb(p[j].x, 24);
      a4 += ws * sb(p[j].y, 0);
      a5 += ws * sb(p[j].y, 8);
      a6 += ws * sb(p[j].y, 16);
      a7 += ws * sb(p[j].y, 24);
    }
  }
  float rw = 1.f / wsum;
  float v0 = a0 * rw + bias[c0 + 0];
  float v1 = a1 * rw + bias[c0 + 1];
  float v2 = a2 * rw + bias[c0 + 2];
  float v3 = a3 * rw + bias[c0 + 3];
  float v4 = a4 * rw + bias[c0 + 4];
  float v5 = a5 * rw + bias[c0 + 5];
  float v6 = a6 * rw + bias[c0 + 6];
  float v7 = a7 * rw + bias[c0 + 7];
  v0 = v0 > 0.f ? v0 : (__expf(v0) - 1.f);
  v1 = v1 > 0.f ? v1 : (__expf(v1) - 1.f);
  v2 = v2 > 0.f ? v2 : (__expf(v2) - 1.f);
  v3 = v3 > 0.f ? v3 : (__expf(v3) - 1.f);
  v4 = v4 > 0.f ? v4 : (__expf(v4) - 1.f);
  v5 = v5 > 0.f ? v5 : (__expf(v5) - 1.f);
  v6 = v6 > 0.f ? v6 : (__expf(v6) - 1.f);
  v7 = v7 > 0.f ? v7 : (__expf(v7) - 1.f);
  float s1 = ((v0 + v1) + (v2 + v3)) + ((v4 + v5) + (v6 + v7));
  float s2 = ((v0 * v0 + v1 * v1) + (v2 * v2 + v3 * v3)) +
             ((v4 * v4 + v5 * v5) + (v6 * v6 + v7 * v7));
#pragma unroll
  for (int o = 8; o > 0; o >>= 1) {
    s1 += __shfl_down(s1, o, 16);
    s2 += __shfl_down(s2, o, 16);
  }
  s1 = __shfl(s1, 0, 16);
  s2 = __shfl(s2, 0, 16);
  float mu = s1 * (1.f / HID);
  float var = s2 * (1.f / HID) - mu * mu;
  float inv = rsqrtf(var + LN_EPS);
  ushort4 q0, q1;
  q0.x = f2bf((v0 - mu) * inv * g[c0 + 0] + beta[c0 + 0]);
  q0.y = f2bf((v1 - mu) * inv * g[c0 + 1] + beta[c0 + 1]);
  q0.z = f2bf((v2 - mu) * inv * g[c0 + 2] + beta[c0 + 2]);
  q0.w = f2bf((v3 - mu) * inv * g[c0 + 3] + beta[c0 + 3]);
  q1.x = f2bf((v4 - mu) * inv * g[c0 + 4] + beta[c0 + 4]);
  q1.y = f2bf((v5 - mu) * inv * g[c0 + 5] + beta[c0 + 5]);
  q1.z = f2bf((v6 - mu) * inv * g[c0 + 6] + beta[c0 + 6]);
  q1.w = f2bf((v7 - mu) * inv * g[c0 + 7] + beta[c0 + 7]);
  *(ushort4*)(outb + (size_t)d * HID + c0) = q0;
  *(ushort4*)(outb + (size_t)d * HID + c0 + 4) = q1;
}

// ---------------------------------------------------------------------------
// Fused GAT agg + bias + ELU + LN, layer 2 (1 head). bf16 payload.
// (R3-verified)
// ---------------------------------------------------------------------------
__global__ __launch_bounds__(256) void k_agg2(
    const int* __restrict__ rowstart, const int* __restrict__ csr_src,
    const float* __restrict__ asrc, const float* __restrict__ adst,
    const unsigned short* __restrict__ hb, const float* __restrict__ bias,
    const float* __restrict__ g, const float* __restrict__ beta,
    float* __restrict__ out, int N) {
  int d = blockIdx.x * 16 + (threadIdx.x >> 4);
  if (d >= N) return;
  int lane = threadIdx.x & 15;
  int c0 = lane << 3;
  float ad = adst[d];
  int beg = rowstart[d], end = rowstart[d + 1];
  float a0 = 0.f, a1 = 0.f, a2 = 0.f, a3 = 0.f;
  float a4 = 0.f, a5 = 0.f, a6 = 0.f, a7 = 0.f, wsum = 0.f;
  for (int i = beg; i < end; i += 8) {
    int s[8];
#pragma unroll
    for (int j = 0; j < 8; ++j) {
      int e = i + j;
      s[j] = csr_src[e < end ? e : end - 1];
    }
    float lg[8];
    uint4 p[8];
#pragma unroll
    for (int j = 0; j < 8; ++j) lg[j] = asrc[s[j]];
#pragma unroll
    for (int j = 0; j < 8; ++j)
      p[j] = *(const uint4*)(hb + (size_t)s[j] * HID + c0);
    float wv[8];
#pragma unroll
    for (int j = 0; j < 8; ++j) {
      float v = lg[j] + ad;
      v = v < 0.f ? NEG * v : v;
      float ex = __expf(v);
      wv[j] = (i + j < end) ? ex : 0.f;
    }
    wsum += ((wv[0] + wv[1]) + (wv[2] + wv[3])) +
            ((wv[4] + wv[5]) + (wv[6] + wv[7]));
#pragma unroll
    for (int j = 0; j < 8; ++j) {
      a0 += wv[j] * bflo(p[j].x);
      a1 += wv[j] * bfhi(p[j].x);
      a2 += wv[j] * bflo(p[j].y);
      a3 += wv[j] * bfhi(p[j].y);
      a4 += wv[j] * bflo(p[j].z);
      a5 += wv[j] * bfhi(p[j].z);
      a6 += wv[j] * bflo(p[j].w);
      a7 += wv[j] * bfhi(p[j].w);
    }
  }
  float rw = 1.f / wsum;
  float v0 = a0 * rw + bias[c0 + 0];
  float v1 = a1 * rw + bias[c0 + 1];
  float v2 = a2 * rw + bias[c0 + 2];
  float v3 = a3 * rw + bias[c0 + 3];
  float v4 = a4 * rw + bias[c0 + 4];
  float v5 = a5 * rw + bias[c0 + 5];
  float v6 = a6 * rw + bias[c0 + 6];
  float v7 = a7 * rw + bias[c0 + 7];
  v0 = v0 > 0.f ? v0 : (__expf(v0) - 1.f);
  v1 = v1 > 0.f ? v1 : (__expf(v1) - 1.f);
  v2 = v2 > 0.f ? v2 : (__expf(v2) - 1.f);
  v3 = v3 > 0.f ? v3 : (__expf(v3) - 1.f);
  v4 = v4 > 0.f ? v4 : (__expf(v4) - 1.f);
  v5 = v5 > 0.f ? v5 : (__expf(v5) - 1.f);
  v6 = v6 > 0.f ? v6 : (__expf(v6) - 1.f);
  v7 = v7 > 0.f ? v7 : (__expf(v7) - 1.f);
  float s1 = ((v0 + v1) + (v2 + v3)) + ((v4 + v5) + (v6 + v7));
  float s2 = ((v0 * v0 + v1 * v1) + (v2 * v2 + v3 * v3)) +
             ((v4 * v4 + v5 * v5) + (v6 * v6 + v7 * v7));
#pragma unroll
  for (int o = 8; o > 0; o >>= 1) {
    s1 += __shfl_down(s1, o, 16);
    s2 += __shfl_down(s2, o, 16);
  }
  s1 = __shfl(s1, 0, 16);
  s2 = __shfl(s2, 0, 16);
  float mu = s1 * (1.f / HID);
  float var = s2 * (1.f / HID) - mu * mu;
  float inv = rsqrtf(var + LN_EPS);
  float4 o0, o1;
  o0.x = (v0 - mu) * inv * g[c0 + 0] + beta[c0 + 0];
  o0.y = (v1 - mu) * inv * g[c0 + 1] + beta[c0 + 1];
  o0.z = (v2 - mu) * inv * g[c0 + 2] + beta[c0 + 2];
  o0.w = (v3 - mu) * inv * g[c0 + 3] + beta[c0 + 3];
  o1.x = (v4 - mu) * inv * g[c0 + 4] + beta[c0 + 4];
  o1.y = (v5 - mu) * inv * g[c0 + 5] + beta[c0 + 5];
  o1.z = (v6 - mu) * inv * g[c0 + 6] + beta[c0 + 6];
  o1.w = (v7 - mu) * inv * g[c0 + 7] + beta[c0 + 7];
  *(float4*)(out + (size_t)d * HID + c0) = o0;
  *(float4*)(out + (size_t)d * HID + c0 + 4) = o1;
}

// ---------------------------------------------------------------------------
// Pack W2 into MFMA B-fragment order, bf16 hi+lo. (R1-verified)
// ---------------------------------------------------------------------------
__global__ __launch_bounds__(256) void k_w2pack(
    const float* __restrict__ W2, unsigned short* __restrict__ w2hi,
    unsigned short* __restrict__ w2lo) {
  int idx = blockIdx.x * 256 + threadIdx.x;  // 16384 total
  int i = idx & 7;
  int lane = (idx >> 3) & 63;
  int t = (idx >> 9) & 7;
  int kb = idx >> 12;
  int k = kb * 32 + (lane >> 4) * 8 + i;
  int c = t * 16 + (lane & 15);
  float w = W2[k * HID + c];
  unsigned short hi = f2bf(w);
  float res = w - bf2f(hi);
  w2hi[idx] = hi;
  w2lo[idx] = f2bf(res);
}

// ---------------------------------------------------------------------------
// h2 = x2 @ W2 via MFMA bf16 (hi+lo split). (R3-verified; h2b no longer
// overlays x2b -- R4 had a latent write/read race there.)
// ---------------------------------------------------------------------------
__global__ __launch_bounds__(256) void k_gemm2m(
    const unsigned short* __restrict__ x2b,
    const unsigned short* __restrict__ w2hi,
    const unsigned short* __restrict__ w2lo,
    const float* __restrict__ a_src, const float* __restrict__ a_dst,
    unsigned short* __restrict__ h2b, float* __restrict__ asrc,
    float* __restrict__ adst, int N) {
  __shared__ float cs[4][16][132];
  int w = threadIdx.x >> 6;
  int l = threadIdx.x & 63;
  int n0 = blockIdx.x * 128 + w * 32;
  int m = l & 15;    // A row within tile
  int kg = l >> 4;   // k-group
  int naA = n0 + m;
  if (naA >= N) naA = N - 1;  // clamp loads; garbage rows never stored
  int naB = n0 + 16 + m;
  if (naB >= N) naB = N - 1;
  const unsigned short* xA = x2b + (size_t)naA * HID + kg * 8;
  const unsigned short* xB = x2b + (size_t)naB * HID + kg * 8;
  f32x4 accA[8] = {};
  f32x4 accB[8] = {};
#pragma unroll
  for (int kb = 0; kb < 4; ++kb) {
    bf16x8 aA = *(const bf16x8*)(xA + kb * 32);
    bf16x8 aB = *(const bf16x8*)(xB + kb * 32);
#pragma unroll
    for (int t = 0; t < 8; ++t) {
      bf16x8 bl = *(const bf16x8*)(w2lo + ((kb * 8 + t) * 64 + l) * 8);
      bf16x8 bh = *(const bf16x8*)(w2hi + ((kb * 8 + t) * 64 + l) * 8);
      accA[t] = __builtin_amdgcn_mfma_f32_16x16x32_bf16(aA, bl, accA[t], 0, 0, 0);
      accA[t] = __builtin_amdgcn_mfma_f32_16x16x32_bf16(aA, bh, accA[t], 0, 0, 0);
      accB[t] = __builtin_amdgcn_mfma_f32_16x16x32_bf16(aB, bl, accB[t], 0, 0, 0);
      accB[t] = __builtin_amdgcn_mfma_f32_16x16x32_bf16(aB, bh, accB[t], 0, 0, 0);
    }
  }
  // C/D layout (measured): col = lane&15, row = (lane>>4)*4 + reg.
  auto epilog = [&](const f32x4(&acc)[8], int noff) {
#pragma unroll
    for (int t = 0; t < 8; ++t)
#pragma unroll
      for (int j = 0; j < 4; ++j) cs[w][kg * 4 + j][t * 16 + m] = acc[t][j];
    __syncthreads();
    int r2 = l & 15;
    int q = l >> 4;
    int n = n0 + noff + r2;
    if (n < N) {
      const float* rowp = &cs[w][r2][0];
      float pa = 0.f, pd = 0.f;
#pragma unroll
      for (int j = 0; j < 8; ++j) {
        int cc = q * 32 + j * 4;
        float4 v = *(const float4*)(rowp + cc);
        float4 as = *(const float4*)(a_src + cc);
        float4 av = *(const float4*)(a_dst + cc);
        pa += v.x * as.x + v.y * as.y + v.z * as.z + v.w * as.w;
        pd += v.x * av.x + v.y * av.y + v.z * av.z + v.w * av.w;
        ushort4 ob;
        ob.x = f2bf(v.x);
        ob.y = f2bf(v.y);
        ob.z = f2bf(v.z);
        ob.w = f2bf(v.w);
        *(ushort4*)(h2b + (size_t)n * HID + cc) = ob;
      }
      pa += __shfl_xor(pa, 16, 64);
      pa += __shfl_xor(pa, 32, 64);
      pd += __shfl_xor(pd, 16, 64);
      pd += __shfl_xor(pd, 32, 64);
      if (q == 0) {
        asrc[n] = pa;
        adst[n] = pd;
      }
    }
    __syncthreads();
  };
  epilog(accA, 0);
  epilog(accB, 16);
}

extern "C" void kernel_launch(void* const* d_in, const int* in_sizes, int n_in,
                              void* d_out, int out_size, void* d_ws, size_t ws_size,
                              hipStream_t stream) {
  const float* x      = (const float*)d_in[0];
  const int*   ei     = (const int*)d_in[1];
  const float* W1     = (const float*)d_in[2];
  const float* a_src1 = (const float*)d_in[3];
  const float* a_dst1 = (const float*)d_in[4];
  const float* b1     = (const float*)d_in[5];
  const float* g1     = (const float*)d_in[6];
  const float* beta1  = (const float*)d_in[7];
  const float* W2     = (const float*)d_in[8];
  const float* a_src2 = (const float*)d_in[9];
  const float* a_dst2 = (const float*)d_in[10];
  const float* b2     = (const float*)d_in[11];
  const float* g2     = (const float*)d_in[12];
  const float* beta2  = (const float*)d_in[13];
  float* out = (float*)d_out;

  const int N = in_sizes[0] / IN_CH;
  const int E = in_sizes[1] / 2;
  const int Etot = E + N;

  // bucketed CSR geometry
  const int NBK = (N + 255) >> 8;          // buckets of 256 nodes (391)
  const int NBLK = (Etot + 8191) >> 13;    // 8192-edge chunks (208)
  const int M = NBK * NBLK;                // count-matrix size (81328)
  const int Mblk = (M + 255) / 256;        // scan blocks (318 <= 512)

  // workspace layout (separate regions; no overlays)
  unsigned char* U = (unsigned char*)d_ws;
  signed char* hq = (signed char*)U;                       // N*HID int8
  float* rec = (float*)(U + (size_t)N * HID);              // N*8 f32
  unsigned short* x2b =
      (unsigned short*)(U + (size_t)N * HID + (size_t)N * 32);  // N*HID bf16
  unsigned short* h2b = x2b + (size_t)N * HID;             // N*HID bf16
  float* adst1 = (float*)(h2b + (size_t)N * HID);
  float* asrc2 = adst1 + (size_t)N * HEADS;
  float* adst2 = asrc2 + N;
  int* rowstart = (int*)(adst2 + N);   // [N+1] padded to N+4
  int* aux      = rowstart + N + 4;    // [<=1024]
  int* bcnt     = aux + 1024;          // [M]
  int* bpart    = bcnt + M;            // [M]
  int* bpre     = bpart + M;           // [M]
  unsigned* bbuf = (unsigned*)(bpre + M);  // [Etot]
  int* csr_src  = (int*)(bbuf + Etot);     // [Etot]
  unsigned short* w2hi = (unsigned short*)(csr_src + Etot);  // [16384]
  unsigned short* w2lo = w2hi + 16384;                       // [16384]

  // ---- W2 fragment pack (independent of everything else) ----
  k_w2pack<<<64, 256, 0, stream>>>(W2, w2hi, w2lo);

  // ---- bucketed CSR build (zero global atomics) ----
  k_hist<<<NBLK, 256, 0, stream>>>(ei, E, Etot, NBK, NBLK, bcnt);
  k_scan1<<<Mblk, 256, 0, stream>>>(bcnt, bpart, aux, M);
  k_scan2<<<1, 512, 0, stream>>>(aux, Mblk);
  k_scan3g<<<Mblk, 256, 0, stream>>>(bpart, aux, bpre, M);
  k_bucket<<<NBLK, 256, 0, stream>>>(ei, bpre, E, Etot, NBK, NBLK, bbuf);
  k_build<<<NBK, 256, 0, stream>>>(bbuf, bpre, rowstart, csr_src, N, Etot,
                                   NBK, NBLK);

  // ---- Layer 1 ----
  k_gemm1<<<N, 128, 0, stream>>>(x, W1, a_src1, a_dst1, hq, rec, adst1, N);
  k_agg1<<<(N + 15) / 16, 256, 0, stream>>>(rowstart, csr_src, rec, adst1, hq,
                                            b1, g1, beta1, x2b, N);

  // ---- Layer 2 ----
  k_gemm2m<<<(N + 127) / 128, 256, 0, stream>>>(x2b, w2hi, w2lo, a_src2,
                                                a_dst2, h2b, asrc2, adst2, N);
  k_agg2<<<(N + 15) / 16, 256, 0, stream>>>(rowstart, csr_src, asrc2, adst2,
                                            h2b, b2, g2, beta2, out, N);
}

// Round 6
// 304.900 us; speedup vs baseline: 1.3295x; 1.1721x over previous
//
#include <hip/hip_runtime.h>

#define IN_CH 16
#define HID 128
#define HEADS 4
#define NEG 0.2f
#define LN_EPS 1e-5f
#define BCAP 8192  // max edges per 256-node bucket (mean ~4400, +55 sigma)

typedef short bf16x8 __attribute__((ext_vector_type(8)));
typedef float f32x4 __attribute__((ext_vector_type(4)));

__device__ __forceinline__ float bf2f(unsigned short u) {
  return __uint_as_float(((unsigned)u) << 16);
}
__device__ __forceinline__ float bflo(unsigned u) {
  return __uint_as_float(u << 16);
}
__device__ __forceinline__ float bfhi(unsigned u) {
  return __uint_as_float(u & 0xffff0000u);
}
__device__ __forceinline__ unsigned short f2bf(float f) {
  unsigned u = __float_as_uint(f);
  unsigned r = (u + 0x7fffu + ((u >> 16) & 1u)) >> 16;  // RNE
  return (unsigned short)r;
}
// sign-extended byte -> float. sh in {0,8,16,24}.
__device__ __forceinline__ float sb(unsigned v, int sh) {
  return (float)((int)(v << (24 - sh)) >> 24);
}

// ---------------------------------------------------------------------------
// h1 = x @ W1 -> int8 (per-node scale), fused attention logits.
// 8 nodes/block, W1 staged in LDS, float4 columns. Same k-order as R4.
// rec[n*8] = {asrc[0..3], scale, pad}.
// ---------------------------------------------------------------------------
__global__ __launch_bounds__(256) void k_gemm1(
    const float* __restrict__ x, const float* __restrict__ W1,
    const float* __restrict__ a_src, const float* __restrict__ a_dst,
    signed char* __restrict__ hq, float* __restrict__ rec,
    float* __restrict__ adst, int N) {
  __shared__ float w1s[IN_CH][HID];
  __shared__ float xsh[8][IN_CH];
  int tid = threadIdx.x;
  int nb = blockIdx.x * 8;
  for (int i = tid; i < IN_CH * HID; i += 256) ((float*)w1s)[i] = W1[i];
  if (tid < 128) {
    int nl = tid >> 4, k = tid & 15;
    int n = nb + nl;
    xsh[nl][k] = (n < N) ? x[n * IN_CH + k] : 0.f;
  }
  __syncthreads();
  int nl = tid >> 5;
  int l32 = tid & 31;
  int c0 = l32 << 2;
  int n = nb + nl;
  float4 acc = make_float4(0.f, 0.f, 0.f, 0.f);
#pragma unroll
  for (int k = 0; k < IN_CH; ++k) {
    float xv = xsh[nl][k];
    float4 wv = *(const float4*)(&w1s[k][c0]);
    acc.x += xv * wv.x;
    acc.y += xv * wv.y;
    acc.z += xv * wv.z;
    acc.w += xv * wv.w;
  }
  float4 as4 = *(const float4*)(a_src + c0);
  float4 ad4 = *(const float4*)(a_dst + c0);
  float av = acc.x * as4.x + acc.y * as4.y + acc.z * as4.z + acc.w * as4.w;
  float dv = acc.x * ad4.x + acc.y * ad4.y + acc.z * ad4.z + acc.w * ad4.w;
  av += __shfl_xor(av, 1);
  av += __shfl_xor(av, 2);
  av += __shfl_xor(av, 4);
  dv += __shfl_xor(dv, 1);
  dv += __shfl_xor(dv, 2);
  dv += __shfl_xor(dv, 4);
  float m = fmaxf(fmaxf(fabsf(acc.x), fabsf(acc.y)),
                  fmaxf(fabsf(acc.z), fabsf(acc.w)));
#pragma unroll
  for (int o = 1; o < 32; o <<= 1) m = fmaxf(m, __shfl_xor(m, o));
  if (n < N) {
    float rs = (m > 0.f) ? 127.f / m : 0.f;
    int b0 = __float2int_rn(acc.x * rs) & 255;
    int b1 = __float2int_rn(acc.y * rs) & 255;
    int b2 = __float2int_rn(acc.z * rs) & 255;
    int b3 = __float2int_rn(acc.w * rs) & 255;
    *(unsigned*)(hq + (size_t)n * HID + c0) =
        (unsigned)(b0 | (b1 << 8) | (b2 << 16) | (b3 << 24));
    if ((l32 & 7) == 0) {
      rec[n * 8 + (l32 >> 3)] = av;
      adst[n * HEADS + (l32 >> 3)] = dv;
    }
    if (l32 == 0) rec[n * 8 + 4] = m * (1.f / 127.f);
  }
}

// ---------------------------------------------------------------------------
// CSR build, pass A: per-(bucket, block) histogram. (R5-verified)
// ---------------------------------------------------------------------------
__global__ __launch_bounds__(256) void k_hist(
    const int* __restrict__ ei, int E, int Etot, int NBK, int NBLK,
    int* __restrict__ bcnt) {
  __shared__ int lh[512];
  int blk = blockIdx.x;
  for (int i = threadIdx.x; i < 512; i += 256) lh[i] = 0;
  __syncthreads();
  int s0 = blk * 8192, s1 = min(s0 + 8192, Etot);
  for (int e = s0 + threadIdx.x; e < s1; e += 256) {
    int d = (e < E) ? ei[E + e] : (e - E);
    atomicAdd(&lh[d >> 8], 1);
  }
  __syncthreads();
  for (int i = threadIdx.x; i < NBK; i += 256) bcnt[i * NBLK + blk] = lh[i];
}

__global__ __launch_bounds__(256) void k_scan1(
    const int* __restrict__ deg, int* __restrict__ part, int* __restrict__ aux,
    int N) {
  int i = blockIdx.x * 256 + threadIdx.x;
  int v = (i < N) ? deg[i] : 0;
  int lane = threadIdx.x & 63, w = threadIdx.x >> 6;
  int inc = v;
#pragma unroll
  for (int o = 1; o < 64; o <<= 1) {
    int t = __shfl_up(inc, o, 64);
    if (lane >= o) inc += t;
  }
  __shared__ int wsum[4];
  if (lane == 63) wsum[w] = inc;
  __syncthreads();
  int woff = 0;
#pragma unroll
  for (int k = 0; k < 4; ++k)
    if (k < w) woff += wsum[k];
  if (i < N) part[i] = woff + inc - v;
  if (threadIdx.x == 255) aux[blockIdx.x] = woff + inc;
}

__global__ __launch_bounds__(512) void k_scan2(int* __restrict__ aux, int nb) {
  int i = threadIdx.x;
  int v = (i < nb) ? aux[i] : 0;
  int lane = i & 63, w = i >> 6;
  int inc = v;
#pragma unroll
  for (int o = 1; o < 64; o <<= 1) {
    int t = __shfl_up(inc, o, 64);
    if (lane >= o) inc += t;
  }
  __shared__ int wsum[8];
  if (lane == 63) wsum[w] = inc;
  __syncthreads();
  int woff = 0;
#pragma unroll
  for (int k = 0; k < 8; ++k)
    if (k < w) woff += wsum[k];
  if (i < nb) aux[i] = woff + inc - v;
}

__global__ __launch_bounds__(256) void k_scan3g(
    const int* __restrict__ part, const int* __restrict__ aux,
    int* __restrict__ out, int M) {
  int i = blockIdx.x * 256 + threadIdx.x;
  if (i < M) out[i] = part[i] + aux[blockIdx.x];
}

// ---------------------------------------------------------------------------
// CSR build, pass C: bucket-contiguous placement. (R5-verified)
// ---------------------------------------------------------------------------
__global__ __launch_bounds__(256) void k_bucket(
    const int* __restrict__ ei, const int* __restrict__ bpre, int E, int Etot,
    int NBK, int NBLK, unsigned* __restrict__ bbuf) {
  __shared__ int lc[512];
  int blk = blockIdx.x;
  for (int i = threadIdx.x; i < NBK; i += 256) lc[i] = bpre[i * NBLK + blk];
  __syncthreads();
  int s0 = blk * 8192, s1 = min(s0 + 8192, Etot);
  for (int e = s0 + threadIdx.x; e < s1; e += 256) {
    int d = (e < E) ? ei[E + e] : (e - E);
    int s = (e < E) ? ei[e] : d;
    int pos = atomicAdd(&lc[d >> 8], 1);
    bbuf[pos] = ((unsigned)s << 8) | (unsigned)(d & 255);
  }
}

// ---------------------------------------------------------------------------
// CSR build, pass D: per-bucket LDS sort -> rowstart + coalesced csr_src.
// (R5-verified)
// ---------------------------------------------------------------------------
__global__ __launch_bounds__(256) void k_build(
    const unsigned* __restrict__ bbuf, const int* __restrict__ bpre,
    int* __restrict__ rowstart, int* __restrict__ csr_src, int N, int Etot,
    int NBK, int NBLK) {
  __shared__ int ldeg[256], lcur[256], wsum[4];
  __shared__ int lout[BCAP];
  int bin = blockIdx.x;
  int base = bpre[bin * NBLK];
  int next = (bin + 1 < NBK) ? bpre[(bin + 1) * NBLK] : Etot;
  int cnt = next - base;
  if (cnt > BCAP) cnt = BCAP;
  int tid = threadIdx.x;
  ldeg[tid] = 0;
  __syncthreads();
  for (int i = tid; i < cnt; i += 256)
    atomicAdd(&ldeg[bbuf[base + i] & 255u], 1);
  __syncthreads();
  int v = ldeg[tid];
  int lane = tid & 63, wv = tid >> 6;
  int inc = v;
#pragma unroll
  for (int o = 1; o < 64; o <<= 1) {
    int t = __shfl_up(inc, o, 64);
    if (lane >= o) inc += t;
  }
  if (lane == 63) wsum[wv] = inc;
  __syncthreads();
  int woff = 0;
#pragma unroll
  for (int k = 0; k < 4; ++k)
    if (k < wv) woff += wsum[k];
  int pre = woff + inc - v;
  int node = bin * 256 + tid;
  if (node < N) rowstart[node] = base + pre;
  lcur[tid] = pre;
  __syncthreads();
  for (int i = tid; i < cnt; i += 256) {
    unsigned u = bbuf[base + i];
    int p = atomicAdd(&lcur[u & 255u], 1);
    lout[p] = (int)(u >> 8);
  }
  __syncthreads();
  for (int i = tid; i < cnt; i += 256) csr_src[base + i] = lout[i];
  if (bin == 0 && tid == 0) rowstart[N] = Etot;
}

// ---------------------------------------------------------------------------
// Fused GAT agg + bias + ELU + LN, layer 1 (4 heads). int8 payload.
// (R4-verified)
// ---------------------------------------------------------------------------
__global__ __launch_bounds__(256) void k_agg1(
    const int* __restrict__ rowstart, const int* __restrict__ csr_src,
    const float* __restrict__ rec, const float* __restrict__ adst,
    const signed char* __restrict__ hq, const float* __restrict__ bias,
    const float* __restrict__ g, const float* __restrict__ beta,
    unsigned short* __restrict__ outb, int N) {
  int d = blockIdx.x * 16 + (threadIdx.x >> 4);
  if (d >= N) return;
  int lane = threadIdx.x & 15;
  int c0 = lane << 3;  // 8 channels per lane
  int hd = lane >> 2;  // head = c0/32
  float ad = adst[d * HEADS + hd];
  int beg = rowstart[d], end = rowstart[d + 1];
  float a0 = 0.f, a1 = 0.f, a2 = 0.f, a3 = 0.f;
  float a4 = 0.f, a5 = 0.f, a6 = 0.f, a7 = 0.f, wsum = 0.f;
  for (int i = beg; i < end; i += 8) {
    int s[8];
#pragma unroll
    for (int j = 0; j < 8; ++j) {
      int e = i + j;
      s[j] = csr_src[e < end ? e : end - 1];
    }
    float lg[8], sc[8];
    uint2 p[8];
#pragma unroll
    for (int j = 0; j < 8; ++j) {
      lg[j] = rec[s[j] * 8 + hd];
      sc[j] = rec[s[j] * 8 + 4];
    }
#pragma unroll
    for (int j = 0; j < 8; ++j)
      p[j] = *(const uint2*)(hq + (size_t)s[j] * HID + c0);
#pragma unroll
    for (int j = 0; j < 8; ++j) {
      float v = lg[j] + ad;
      v = v < 0.f ? NEG * v : v;
      float ex = __expf(v);
      float w = (i + j < end) ? ex : 0.f;
      wsum += w;
      float ws = w * sc[j];
      a0 += ws * sb(p[j].x, 0);
      a1 += ws * sb(p[j].x, 8);
      a2 += ws * sb(p[j].x, 16);
      a3 += ws * sb(p[j].x, 24);
      a4 += ws * sb(p[j].y, 0);
      a5 += ws * sb(p[j].y, 8);
      a6 += ws * sb(p[j].y, 16);
      a7 += ws * sb(p[j].y, 24);
    }
  }
  float rw = 1.f / wsum;
  float v0 = a0 * rw + bias[c0 + 0];
  float v1 = a1 * rw + bias[c0 + 1];
  float v2 = a2 * rw + bias[c0 + 2];
  float v3 = a3 * rw + bias[c0 + 3];
  float v4 = a4 * rw + bias[c0 + 4];
  float v5 = a5 * rw + bias[c0 + 5];
  float v6 = a6 * rw + bias[c0 + 6];
  float v7 = a7 * rw + bias[c0 + 7];
  v0 = v0 > 0.f ? v0 : (__expf(v0) - 1.f);
  v1 = v1 > 0.f ? v1 : (__expf(v1) - 1.f);
  v2 = v2 > 0.f ? v2 : (__expf(v2) - 1.f);
  v3 = v3 > 0.f ? v3 : (__expf(v3) - 1.f);
  v4 = v4 > 0.f ? v4 : (__expf(v4) - 1.f);
  v5 = v5 > 0.f ? v5 : (__expf(v5) - 1.f);
  v6 = v6 > 0.f ? v6 : (__expf(v6) - 1.f);
  v7 = v7 > 0.f ? v7 : (__expf(v7) - 1.f);
  float s1 = ((v0 + v1) + (v2 + v3)) + ((v4 + v5) + (v6 + v7));
  float s2 = ((v0 * v0 + v1 * v1) + (v2 * v2 + v3 * v3)) +
             ((v4 * v4 + v5 * v5) + (v6 * v6 + v7 * v7));
#pragma unroll
  for (int o = 8; o > 0; o >>= 1) {
    s1 += __shfl_down(s1, o, 16);
    s2 += __shfl_down(s2, o, 16);
  }
  s1 = __shfl(s1, 0, 16);
  s2 = __shfl(s2, 0, 16);
  float mu = s1 * (1.f / HID);
  float var = s2 * (1.f / HID) - mu * mu;
  float inv = rsqrtf(var + LN_EPS);
  ushort4 q0, q1;
  q0.x = f2bf((v0 - mu) * inv * g[c0 + 0] + beta[c0 + 0]);
  q0.y = f2bf((v1 - mu) * inv * g[c0 + 1] + beta[c0 + 1]);
  q0.z = f2bf((v2 - mu) * inv * g[c0 + 2] + beta[c0 + 2]);
  q0.w = f2bf((v3 - mu) * inv * g[c0 + 3] + beta[c0 + 3]);
  q1.x = f2bf((v4 - mu) * inv * g[c0 + 4] + beta[c0 + 4]);
  q1.y = f2bf((v5 - mu) * inv * g[c0 + 5] + beta[c0 + 5]);
  q1.z = f2bf((v6 - mu) * inv * g[c0 + 6] + beta[c0 + 6]);
  q1.w = f2bf((v7 - mu) * inv * g[c0 + 7] + beta[c0 + 7]);
  *(ushort4*)(outb + (size_t)d * HID + c0) = q0;
  *(ushort4*)(outb + (size_t)d * HID + c0 + 4) = q1;
}

// ---------------------------------------------------------------------------
// Fused GAT agg + bias + ELU + LN, layer 2 (1 head). int8 payload (new),
// rec2 = {asrc, scale} float2 single 8B gather. Mirrors verified agg1.
// ---------------------------------------------------------------------------
__global__ __launch_bounds__(256) void k_agg2(
    const int* __restrict__ rowstart, const int* __restrict__ csr_src,
    const float2* __restrict__ rec2, const float* __restrict__ adst,
    const signed char* __restrict__ hq2, const float* __restrict__ bias,
    const float* __restrict__ g, const float* __restrict__ beta,
    float* __restrict__ out, int N) {
  int d = blockIdx.x * 16 + (threadIdx.x >> 4);
  if (d >= N) return;
  int lane = threadIdx.x & 15;
  int c0 = lane << 3;
  float ad = adst[d];
  int beg = rowstart[d], end = rowstart[d + 1];
  float a0 = 0.f, a1 = 0.f, a2 = 0.f, a3 = 0.f;
  float a4 = 0.f, a5 = 0.f, a6 = 0.f, a7 = 0.f, wsum = 0.f;
  for (int i = beg; i < end; i += 8) {
    int s[8];
#pragma unroll
    for (int j = 0; j < 8; ++j) {
      int e = i + j;
      s[j] = csr_src[e < end ? e : end - 1];
    }
    float2 r[8];
    uint2 p[8];
#pragma unroll
    for (int j = 0; j < 8; ++j) r[j] = rec2[s[j]];
#pragma unroll
    for (int j = 0; j < 8; ++j)
      p[j] = *(const uint2*)(hq2 + (size_t)s[j] * HID + c0);
#pragma unroll
    for (int j = 0; j < 8; ++j) {
      float v = r[j].x + ad;
      v = v < 0.f ? NEG * v : v;
      float ex = __expf(v);
      float w = (i + j < end) ? ex : 0.f;
      wsum += w;
      float ws = w * r[j].y;
      a0 += ws * sb(p[j].x, 0);
      a1 += ws * sb(p[j].x, 8);
      a2 += ws * sb(p[j].x, 16);
      a3 += ws * sb(p[j].x, 24);
      a4 += ws * sb(p[j].y, 0);
      a5 += ws * sb(p[j].y, 8);
      a6 += ws * sb(p[j].y, 16);
      a7 += ws * sb(p[j].y, 24);
    }
  }
  float rw = 1.f / wsum;
  float v0 = a0 * rw + bias[c0 + 0];
  float v1 = a1 * rw + bias[c0 + 1];
  float v2 = a2 * rw + bias[c0 + 2];
  float v3 = a3 * rw + bias[c0 + 3];
  float v4 = a4 * rw + bias[c0 + 4];
  float v5 = a5 * rw + bias[c0 + 5];
  float v6 = a6 * rw + bias[c0 + 6];
  float v7 = a7 * rw + bias[c0 + 7];
  v0 = v0 > 0.f ? v0 : (__expf(v0) - 1.f);
  v1 = v1 > 0.f ? v1 : (__expf(v1) - 1.f);
  v2 = v2 > 0.f ? v2 : (__expf(v2) - 1.f);
  v3 = v3 > 0.f ? v3 : (__expf(v3) - 1.f);
  v4 = v4 > 0.f ? v4 : (__expf(v4) - 1.f);
  v5 = v5 > 0.f ? v5 : (__expf(v5) - 1.f);
  v6 = v6 > 0.f ? v6 : (__expf(v6) - 1.f);
  v7 = v7 > 0.f ? v7 : (__expf(v7) - 1.f);
  float s1 = ((v0 + v1) + (v2 + v3)) + ((v4 + v5) + (v6 + v7));
  float s2 = ((v0 * v0 + v1 * v1) + (v2 * v2 + v3 * v3)) +
             ((v4 * v4 + v5 * v5) + (v6 * v6 + v7 * v7));
#pragma unroll
  for (int o = 8; o > 0; o >>= 1) {
    s1 += __shfl_down(s1, o, 16);
    s2 += __shfl_down(s2, o, 16);
  }
  s1 = __shfl(s1, 0, 16);
  s2 = __shfl(s2, 0, 16);
  float mu = s1 * (1.f / HID);
  float var = s2 * (1.f / HID) - mu * mu;
  float inv = rsqrtf(var + LN_EPS);
  float4 o0, o1;
  o0.x = (v0 - mu) * inv * g[c0 + 0] + beta[c0 + 0];
  o0.y = (v1 - mu) * inv * g[c0 + 1] + beta[c0 + 1];
  o0.z = (v2 - mu) * inv * g[c0 + 2] + beta[c0 + 2];
  o0.w = (v3 - mu) * inv * g[c0 + 3] + beta[c0 + 3];
  o1.x = (v4 - mu) * inv * g[c0 + 4] + beta[c0 + 4];
  o1.y = (v5 - mu) * inv * g[c0 + 5] + beta[c0 + 5];
  o1.z = (v6 - mu) * inv * g[c0 + 6] + beta[c0 + 6];
  o1.w = (v7 - mu) * inv * g[c0 + 7] + beta[c0 + 7];
  *(float4*)(out + (size_t)d * HID + c0) = o0;
  *(float4*)(out + (size_t)d * HID + c0 + 4) = o1;
}

// ---------------------------------------------------------------------------
// Pack W2 into MFMA B-fragment order, bf16 hi+lo. (R1-verified)
// ---------------------------------------------------------------------------
__global__ __launch_bounds__(256) void k_w2pack(
    const float* __restrict__ W2, unsigned short* __restrict__ w2hi,
    unsigned short* __restrict__ w2lo) {
  int idx = blockIdx.x * 256 + threadIdx.x;  // 16384 total
  int i = idx & 7;
  int lane = (idx >> 3) & 63;
  int t = (idx >> 9) & 7;
  int kb = idx >> 12;
  int k = kb * 32 + (lane >> 4) * 8 + i;
  int c = t * 16 + (lane & 15);
  float w = W2[k * HID + c];
  unsigned short hi = f2bf(w);
  float res = w - bf2f(hi);
  w2hi[idx] = hi;
  w2lo[idx] = f2bf(res);
}

// ---------------------------------------------------------------------------
// h2 = x2 @ W2 via MFMA bf16 (hi+lo split). Epilogue quantizes h2 -> int8
// per-node scale + rec2 = {asrc2, scale}; adst2 separate.
// ---------------------------------------------------------------------------
__global__ __launch_bounds__(256) void k_gemm2m(
    const unsigned short* __restrict__ x2b,
    const unsigned short* __restrict__ w2hi,
    const unsigned short* __restrict__ w2lo,
    const float* __restrict__ a_src, const float* __restrict__ a_dst,
    signed char* __restrict__ hq2, float2* __restrict__ rec2,
    float* __restrict__ adst, int N) {
  __shared__ float cs[4][16][132];
  int w = threadIdx.x >> 6;
  int l = threadIdx.x & 63;
  int n0 = blockIdx.x * 128 + w * 32;
  int m = l & 15;    // A row within tile
  int kg = l >> 4;   // k-group
  int naA = n0 + m;
  if (naA >= N) naA = N - 1;  // clamp loads; garbage rows never stored
  int naB = n0 + 16 + m;
  if (naB >= N) naB = N - 1;
  const unsigned short* xA = x2b + (size_t)naA * HID + kg * 8;
  const unsigned short* xB = x2b + (size_t)naB * HID + kg * 8;
  f32x4 accA[8] = {};
  f32x4 accB[8] = {};
#pragma unroll
  for (int kb = 0; kb < 4; ++kb) {
    bf16x8 aA = *(const bf16x8*)(xA + kb * 32);
    bf16x8 aB = *(const bf16x8*)(xB + kb * 32);
#pragma unroll
    for (int t = 0; t < 8; ++t) {
      bf16x8 bl = *(const bf16x8*)(w2lo + ((kb * 8 + t) * 64 + l) * 8);
      bf16x8 bh = *(const bf16x8*)(w2hi + ((kb * 8 + t) * 64 + l) * 8);
      accA[t] = __builtin_amdgcn_mfma_f32_16x16x32_bf16(aA, bl, accA[t], 0, 0, 0);
      accA[t] = __builtin_amdgcn_mfma_f32_16x16x32_bf16(aA, bh, accA[t], 0, 0, 0);
      accB[t] = __builtin_amdgcn_mfma_f32_16x16x32_bf16(aB, bl, accB[t], 0, 0, 0);
      accB[t] = __builtin_amdgcn_mfma_f32_16x16x32_bf16(aB, bh, accB[t], 0, 0, 0);
    }
  }
  // C/D layout (measured): col = lane&15, row = (lane>>4)*4 + reg.
  auto epilog = [&](const f32x4(&acc)[8], int noff) {
#pragma unroll
    for (int t = 0; t < 8; ++t)
#pragma unroll
      for (int j = 0; j < 4; ++j) cs[w][kg * 4 + j][t * 16 + m] = acc[t][j];
    __syncthreads();
    int r2 = l & 15;
    int q = l >> 4;
    int n = n0 + noff + r2;
    const float* rowp = &cs[w][r2][0];
    float4 v[8];
    float pa = 0.f, pd = 0.f, mx = 0.f;
#pragma unroll
    for (int j = 0; j < 8; ++j) {
      int cc = q * 32 + j * 4;
      v[j] = *(const float4*)(rowp + cc);
      float4 as = *(const float4*)(a_src + cc);
      float4 av = *(const float4*)(a_dst + cc);
      pa += v[j].x * as.x + v[j].y * as.y + v[j].z * as.z + v[j].w * as.w;
      pd += v[j].x * av.x + v[j].y * av.y + v[j].z * av.z + v[j].w * av.w;
      mx = fmaxf(mx, fmaxf(fmaxf(fabsf(v[j].x), fabsf(v[j].y)),
                           fmaxf(fabsf(v[j].z), fabsf(v[j].w))));
    }
    pa += __shfl_xor(pa, 16);
    pa += __shfl_xor(pa, 32);
    pd += __shfl_xor(pd, 16);
    pd += __shfl_xor(pd, 32);
    mx = fmaxf(mx, __shfl_xor(mx, 16));
    mx = fmaxf(mx, __shfl_xor(mx, 32));
    if (n < N) {
      float rs = (mx > 0.f) ? 127.f / mx : 0.f;
      unsigned u[8];
#pragma unroll
      for (int j = 0; j < 8; ++j) {
        int b0 = __float2int_rn(v[j].x * rs) & 255;
        int b1 = __float2int_rn(v[j].y * rs) & 255;
        int b2 = __float2int_rn(v[j].z * rs) & 255;
        int b3 = __float2int_rn(v[j].w * rs) & 255;
        u[j] = (unsigned)(b0 | (b1 << 8) | (b2 << 16) | (b3 << 24));
      }
      *(uint4*)(hq2 + (size_t)n * HID + q * 32) =
          make_uint4(u[0], u[1], u[2], u[3]);
      *(uint4*)(hq2 + (size_t)n * HID + q * 32 + 16) =
          make_uint4(u[4], u[5], u[6], u[7]);
      if (q == 0) {
        rec2[n] = make_float2(pa, mx * (1.f / 127.f));
        adst[n] = pd;
      }
    }
    __syncthreads();
  };
  epilog(accA, 0);
  epilog(accB, 16);
}

extern "C" void kernel_launch(void* const* d_in, const int* in_sizes, int n_in,
                              void* d_out, int out_size, void* d_ws, size_t ws_size,
                              hipStream_t stream) {
  const float* x      = (const float*)d_in[0];
  const int*   ei     = (const int*)d_in[1];
  const float* W1     = (const float*)d_in[2];
  const float* a_src1 = (const float*)d_in[3];
  const float* a_dst1 = (const float*)d_in[4];
  const float* b1     = (const float*)d_in[5];
  const float* g1     = (const float*)d_in[6];
  const float* beta1  = (const float*)d_in[7];
  const float* W2     = (const float*)d_in[8];
  const float* a_src2 = (const float*)d_in[9];
  const float* a_dst2 = (const float*)d_in[10];
  const float* b2     = (const float*)d_in[11];
  const float* g2     = (const float*)d_in[12];
  const float* beta2  = (const float*)d_in[13];
  float* out = (float*)d_out;

  const int N = in_sizes[0] / IN_CH;
  const int E = in_sizes[1] / 2;
  const int Etot = E + N;

  // bucketed CSR geometry
  const int NBK = (N + 255) >> 8;          // buckets of 256 nodes
  const int NBLK = (Etot + 8191) >> 13;    // 8192-edge chunks
  const int M = NBK * NBLK;                // count-matrix size
  const int Mblk = (M + 255) / 256;        // scan blocks (<= 512)

  // workspace layout (separate regions; no overlays)
  unsigned char* U = (unsigned char*)d_ws;
  signed char* hq = (signed char*)U;                       // N*HID int8
  float* rec = (float*)(U + (size_t)N * HID);              // N*8 f32
  unsigned short* x2b =
      (unsigned short*)(U + (size_t)N * HID + (size_t)N * 32);  // N*HID bf16
  signed char* hq2 = (signed char*)(x2b + (size_t)N * HID);     // N*HID int8
  float2* rec2 = (float2*)(hq2 + (size_t)N * HID);         // N float2
  float* adst1 = (float*)(rec2 + N);
  float* adst2 = adst1 + (size_t)N * HEADS;
  int* rowstart = (int*)(adst2 + N);   // [N+1] padded to N+4
  int* aux      = rowstart + N + 4;    // [<=1024]
  int* bcnt     = aux + 1024;          // [M]
  int* bpart    = bcnt + M;            // [M]
  int* bpre     = bpart + M;           // [M]
  unsigned* bbuf = (unsigned*)(bpre + M);  // [Etot]
  int* csr_src  = (int*)(bbuf + Etot);     // [Etot]
  unsigned short* w2hi = (unsigned short*)(csr_src + Etot);  // [16384]
  unsigned short* w2lo = w2hi + 16384;                       // [16384]

  // ---- W2 fragment pack (independent of everything else) ----
  k_w2pack<<<64, 256, 0, stream>>>(W2, w2hi, w2lo);

  // ---- bucketed CSR build (zero global atomics) ----
  k_hist<<<NBLK, 256, 0, stream>>>(ei, E, Etot, NBK, NBLK, bcnt);
  k_scan1<<<Mblk, 256, 0, stream>>>(bcnt, bpart, aux, M);
  k_scan2<<<1, 512, 0, stream>>>(aux, Mblk);
  k_scan3g<<<Mblk, 256, 0, stream>>>(bpart, aux, bpre, M);
  k_bucket<<<NBLK, 256, 0, stream>>>(ei, bpre, E, Etot, NBK, NBLK, bbuf);
  k_build<<<NBK, 256, 0, stream>>>(bbuf, bpre, rowstart, csr_src, N, Etot,
                                   NBK, NBLK);

  // ---- Layer 1 ----
  k_gemm1<<<(N + 7) / 8, 256, 0, stream>>>(x, W1, a_src1, a_dst1, hq, rec,
                                           adst1, N);
  k_agg1<<<(N + 15) / 16, 256, 0, stream>>>(rowstart, csr_src, rec, adst1, hq,
                                            b1, g1, beta1, x2b, N);

  // ---- Layer 2 ----
  k_gemm2m<<<(N + 127) / 128, 256, 0, stream>>>(x2b, w2hi, w2lo, a_src2,
                                                a_dst2, hq2, rec2, adst2, N);
  k_agg2<<<(N + 15) / 16, 256, 0, stream>>>(rowstart, csr_src, rec2, adst2,
                                            hq2, b2, g2, beta2, out, N);
}